// Round 6
// baseline (479.915 us; speedup 1.0000x reference)
//
#include <hip/hip_runtime.h>

typedef unsigned short u16;
typedef unsigned int u32;
typedef __attribute__((ext_vector_type(8))) short bf16x8;
typedef __attribute__((ext_vector_type(4))) float f32x4;
typedef __attribute__((ext_vector_type(4))) u16 u16x4;
typedef __attribute__((ext_vector_type(8))) u16 u16x8;

#define PTOT 131072   // 128 images * 32*32 pixels

// ---------- helpers ----------
static __device__ __forceinline__ float quantf(float v) {
  float q = rintf(v * 128.f);
  q = fmaxf(-127.f, fminf(127.f, q));
  return q * 0.0078125f;
}
static __device__ __forceinline__ u16 f2bf(float v) {   // exact for quant grid
  return (u16)(__float_as_uint(v) >> 16);
}
static __device__ __forceinline__ u16 bf_rne(float v) { // round-nearest-even bf16
  u32 u = __float_as_uint(v);
  u += 0x7fffu + ((u >> 16) & 1u);
  return (u16)(u >> 16);
}
static __device__ __forceinline__ float bf2f(u16 v) {
  return __uint_as_float((u32)v << 16);
}

// ---------- weight quantize + MFMA fragment packing (all 7 convs, 1 launch) ----------
// packed: [NCH][NF][64][8]; co = nf*16+(lane&15), k = c*32+(lane>>4)*8+j over padded CI.
struct WPtrs { const float* p[7]; };

__global__ void wpack_kernel(WPtrs wp, u16* __restrict__ o) {
  // {elem_off, len, CIr, CIp, KH, Co}
  static const int S[7][6] = {
      {0,      12288,  192, 192, 1, 64},  {12288,  18432,  192, 192, 1, 96},
      {30720,  110592, 96,  96,  3, 128}, {141312, 3072,   192, 192, 1, 16},
      {144384, 9216,   16,  32,  3, 32},  {153600, 9216,   32,  32,  3, 32},
      {162816, 6144,   192, 192, 1, 32},
  };
  int idx = blockIdx.x * 256 + threadIdx.x;
  if (idx >= 168960) return;
  int s = 0;
#pragma unroll
  for (int i = 1; i < 7; ++i)
    if (idx >= S[i][0]) s = i;
  int local = idx - S[s][0];
  int CIr = S[s][2], CIp = S[s][3], KH = S[s][4], Co = S[s][5];
  int j = local & 7, lane = (local >> 3) & 63, f = local >> 9;
  int NF = Co >> 4;
  int c = f / NF, nf = f - c * NF;
  int co = nf * 16 + (lane & 15);
  int k = c * 32 + ((lane >> 4) << 3) + j;
  int tap = k / CIp, ci = k - tap * CIp;
  u16 val = 0;
  if (ci < CIr) {
    int kh = tap / 3, kw = tap - kh * 3;
    val = f2bf(quantf(wp.p[s][(((size_t)co * CIr + ci) * KH + kh) * KH + kw]));
  }
  o[idx] = val;
}

// ---------- quantize x: NCHW f32 -> NHWC bf16 ----------
__global__ __launch_bounds__(256) void quantx_kernel(const float* __restrict__ x,
                                                     u16* __restrict__ xq) {
  __shared__ __align__(16) u16 tile[64][72];
  int n = blockIdx.z, hwb = blockIdx.x * 64, cb = blockIdx.y * 64;
  int lane = threadIdx.x & 63, sub = threadIdx.x >> 6;
#pragma unroll
  for (int i = 0; i < 16; ++i) {
    int c = sub + i * 4;
    float v = x[(((size_t)n * 192 + cb + c) << 10) + hwb + lane];
    tile[lane][c] = f2bf(quantf(v));
  }
  __syncthreads();
#pragma unroll
  for (int i = 0; i < 2; ++i) {
    int chunk = threadIdx.x + i * 256;
    int px = chunk >> 3, c8 = chunk & 7;
    uint4 v = *(const uint4*)&tile[px][c8 * 8];
    *(uint4*)&xq[(((size_t)n << 10) + hwb + px) * 192 + cb + c8 * 8] = v;
  }
}

// ---------- maxpool 3x3 s1 p1 on quantized NHWC bf16 ----------
__global__ __launch_bounds__(256) void pool_kernel(const u16* __restrict__ xq,
                                                   u16* __restrict__ xpq) {
  int idx = blockIdx.x * 256 + threadIdx.x;
  int c8 = idx % 24;
  int p = idx / 24;
  int n = p >> 10, hw = p & 1023, h = hw >> 5, w = hw & 31;
  float m[8];
#pragma unroll
  for (int j = 0; j < 8; ++j) m[j] = -1e30f;
  for (int dh = -1; dh <= 1; ++dh) {
    int hh = h + dh; if (hh < 0 || hh > 31) continue;
    for (int dw = -1; dw <= 1; ++dw) {
      int ww = w + dw; if (ww < 0 || ww > 31) continue;
      uint4 v = *(const uint4*)&xq[((((size_t)n << 5) + hh) * 32 + ww) * 192 + c8 * 8];
      u32 a[4] = {v.x, v.y, v.z, v.w};
#pragma unroll
      for (int t = 0; t < 4; ++t) {
        m[t * 2]     = fmaxf(m[t * 2],     __uint_as_float(a[t] << 16));
        m[t * 2 + 1] = fmaxf(m[t * 2 + 1], __uint_as_float(a[t] & 0xffff0000u));
      }
    }
  }
  uint4 o;
  u32* oa = &o.x;
#pragma unroll
  for (int t = 0; t < 4; ++t)
    oa[t] = (u32)f2bf(m[t * 2]) | ((u32)f2bf(m[t * 2 + 1]) << 16);
  *(uint4*)&xpq[(size_t)p * 192 + c8 * 8] = o;
}

// ---------- MFMA conv + bf16 y-hat write + fused per-channel stats ----------
// xin bf16: KK==1: [PTOT][CI]; KK==9: [128][34][34][CI] zero-padded.
// bp: packed B fragments; nft = branch NF total, nf0 = fragment offset.
// st (pre-offset to this launch's channel slice), yh (pre-offset likewise).
template <int CI, int KK, int COB>
__global__ __launch_bounds__(256, 2) void cstat_kernel(
    const u16* __restrict__ xin, const u16* __restrict__ bp, int nft, int nf0,
    double* __restrict__ st, u16* __restrict__ yh) {
  constexpr int NCH = KK * CI / 32;
  constexpr int NFW = COB / 16;
  constexpr int MF = 4;

  const int lane = threadIdx.x & 63;
  const int wave = threadIdx.x >> 6;
  const int mbase = blockIdx.x * 256 + wave * 64;

  uint abase[MF];
#pragma unroll
  for (int mf = 0; mf < MF; ++mf) {
    int p = mbase + mf * 16 + (lane & 15);
    if (KK == 1) {
      abase[mf] = (uint)p * (CI * 2);
    } else {
      int n = p >> 10, hw = p & 1023, h = hw >> 5, w = hw & 31;
      abase[mf] = (uint)((n * 34 + h) * 34 + w) * (CI * 2);
    }
  }
  const uint klane = (uint)(lane >> 4) * 16u;
  const uint blane = (uint)lane * 16u;

  f32x4 acc[MF][NFW];
#pragma unroll
  for (int i = 0; i < MF; ++i)
#pragma unroll
    for (int j = 0; j < NFW; ++j) acc[i][j] = {0.f, 0.f, 0.f, 0.f};

  auto chunk = [&](int c) {
    uint koff;
    if (KK == 1) {
      koff = (uint)c * 64u;
    } else {
      int tap = (c * 32) / CI, ci0 = (c * 32) % CI;
      koff = (uint)(((tap / 3) * 34 + (tap % 3)) * CI + ci0) * 2u;
    }
    bf16x8 af[MF];
#pragma unroll
    for (int mf = 0; mf < MF; ++mf)
      af[mf] = *(const bf16x8*)((const char*)xin + (abase[mf] + koff + klane));
    bf16x8 bfr[NFW];
#pragma unroll
    for (int nf = 0; nf < NFW; ++nf)
      bfr[nf] = *(const bf16x8*)((const char*)bp +
                                 ((uint)((c * nft + nf0 + nf) * 1024) + blane));
#pragma unroll
    for (int mf = 0; mf < MF; ++mf)
#pragma unroll
      for (int nf = 0; nf < NFW; ++nf)
        acc[mf][nf] = __builtin_amdgcn_mfma_f32_16x16x32_bf16(af[mf], bfr[nf],
                                                              acc[mf][nf], 0, 0, 0);
  };

  if (KK == 1) {
#pragma unroll
    for (int c = 0; c < NCH; ++c) chunk(c);
  } else {
#pragma unroll 3
    for (int c = 0; c < NCH; ++c) chunk(c);
  }

  // ---- write y-hat bf16 planar [co_local][PTOT] ----
#pragma unroll
  for (int mf = 0; mf < MF; ++mf)
#pragma unroll
    for (int nf = 0; nf < NFW; ++nf) {
      int col = nf * 16 + (lane & 15);
      int pix = mbase + mf * 16 + ((lane >> 4) << 2);
      u16x4 o;
#pragma unroll
      for (int r = 0; r < 4; ++r) o[r] = bf_rne(acc[mf][nf][r]);
      *(u16x4*)&yh[(size_t)col * PTOT + pix] = o;
    }

  // ---- per-channel stats over this block's 256 px -> f64 atomics ----
  float s1[NFW], s2[NFW];
#pragma unroll
  for (int nf = 0; nf < NFW; ++nf) { s1[nf] = 0.f; s2[nf] = 0.f; }
#pragma unroll
  for (int mf = 0; mf < MF; ++mf)
#pragma unroll
    for (int nf = 0; nf < NFW; ++nf)
#pragma unroll
      for (int r = 0; r < 4; ++r) {
        float v = acc[mf][nf][r];
        s1[nf] += v;
        s2[nf] += v * v;
      }
#pragma unroll
  for (int m = 16; m <= 32; m <<= 1)
#pragma unroll
    for (int nf = 0; nf < NFW; ++nf) {
      s1[nf] += __shfl_xor(s1[nf], m);
      s2[nf] += __shfl_xor(s2[nf], m);
    }
  __shared__ float red[4][NFW][16][2];
  if (lane < 16)
#pragma unroll
    for (int nf = 0; nf < NFW; ++nf) {
      red[wave][nf][lane][0] = s1[nf];
      red[wave][nf][lane][1] = s2[nf];
    }
  __syncthreads();
  const int t = threadIdx.x;
  if (t < COB) {
    int nf = t >> 4, l = t & 15;
    float a = red[0][nf][l][0] + red[1][nf][l][0] + red[2][nf][l][0] + red[3][nf][l][0];
    float b = red[0][nf][l][1] + red[1][nf][l][1] + red[2][nf][l][1] + red[3][nf][l][1];
    atomicAdd(&st[2 * t], (double)a);
    atomicAdd(&st[2 * t + 1], (double)b);
  }
}

// ---------- BN+ReLU -> final f32 NCHW out; coefs inline from stats ----------
__global__ __launch_bounds__(256) void bnout_kernel(const u16* __restrict__ yh,
                                                    const double* __restrict__ st,
                                                    const float* __restrict__ g,
                                                    const float* __restrict__ be,
                                                    float* __restrict__ out, int cog) {
  int co = blockIdx.y, chunk = blockIdx.x, tid = threadIdx.x;
  double m = st[2 * co] * (1.0 / PTOT);
  double v = st[2 * co + 1] * (1.0 / PTOT) - m * m;
  double inv = 1.0 / sqrt(v + 1e-5);
  double c0d = (double)g[co] * inv;
  float c0 = (float)c0d;
  float c1 = (float)((double)be[co] - m * c0d);

  int p0 = chunk * 4096 + tid * 16;
  int n = p0 >> 10, hw = p0 & 1023;
  const u16* yp = yh + (size_t)co * PTOT + p0;
  float* op = out + (((size_t)(n * 256 + cog + co)) << 10) + hw;
#pragma unroll
  for (int half = 0; half < 2; ++half) {
    u16x8 r = *(const u16x8*)(yp + half * 8);
    f32x4 a, b;
#pragma unroll
    for (int e = 0; e < 4; ++e) {
      a[e] = fmaxf(fmaf(bf2f(r[e]), c0, c1), 0.f);
      b[e] = fmaxf(fmaf(bf2f(r[e + 4]), c0, c1), 0.f);
    }
    *(f32x4*)(op + half * 8) = a;
    *(f32x4*)(op + half * 8 + 4) = b;
  }
}

// ---------- BN+ReLU+quantize -> padded NHWC bf16; coefs inline ----------
template <int CO, int COP>
__global__ __launch_bounds__(256) void bnqpad_kernel(const u16* __restrict__ yh,
                                                     const double* __restrict__ st,
                                                     const float* __restrict__ g,
                                                     const float* __restrict__ be,
                                                     u16* __restrict__ q) {
  __shared__ float2 cfl[CO];
  __shared__ __align__(16) u16 tile[64][COP + 8];
  const int t = threadIdx.x;
  if (t < CO) {
    double m = st[2 * t] * (1.0 / PTOT);
    double v = st[2 * t + 1] * (1.0 / PTOT) - m * m;
    double inv = 1.0 / sqrt(v + 1e-5);
    double c0 = (double)g[t] * inv;
    cfl[t] = make_float2((float)c0, (float)((double)be[t] - m * c0));
  }
  __syncthreads();
  int p0 = blockIdx.x * 64;
  int lane = t & 63, sub = t >> 6;
#pragma unroll
  for (int i = 0; i < COP / 4; ++i) {
    int co = sub + i * 4;
    u16 outv = 0;
    if (CO == COP || co < CO) {
      float2 cc = cfl[co];
      float yv = bf2f(yh[(size_t)co * PTOT + p0 + lane]);
      float z = fmaxf(fmaf(yv, cc.x, cc.y), 0.f);
      float qv = fminf(rintf(z * 128.f), 127.f) * 0.0078125f;  // z>=0 after relu
      outv = f2bf(qv);
    }
    tile[lane][co] = outv;
  }
  __syncthreads();
  for (int chunk = t; chunk < 64 * (COP / 8); chunk += 256) {
    int px = chunk / (COP / 8), c8 = chunk % (COP / 8);
    int p = p0 + px;
    int n = p >> 10, hw = p & 1023, h = hw >> 5, w = hw & 31;
    size_t dst = (((size_t)n * 34 + h + 1) * 34 + (w + 1)) * COP + c8 * 8;
    *(uint4*)&q[dst] = *(const uint4*)&tile[px][c8 * 8];
  }
}

extern "C" void kernel_launch(void* const* d_in, const int* in_sizes, int n_in,
                              void* d_out, int out_size, void* d_ws, size_t ws_size,
                              hipStream_t stream) {
  const float* x = (const float*)d_in[0];
  float* out = (float*)d_out;
  char* ws = (char*)d_ws;

  // ---- workspace layout (total 134,569,984 B) ----
  // xpq truly spans [50331648, 100663296): yh MUST start at/after 100663296.
  if (ws_size < 134569984ull) return;
  u16* xq  = (u16*)ws;                       // [PTOT][192] bf16      = 50,331,648 B
  u16* xpq = (u16*)(ws + 50331648ull);       // pooled [PTOT][192]    = 50,331,648 B
  u16* q2a = xpq;                            // reuse: [128][34][34][96] = 28,409,856 B
  u16* q3a = (u16*)(ws + 78741504ull);       // reuse: [128][34][34][32] =  9,469,952 B
  u16* q3b = (u16*)(ws + 88211456ull);       // reuse: [128][34][34][32] =  9,469,952 B
  u16* yh  = (u16*)(ws + 100663296ull);      // [<=128][PTOT] bf16    = 33,554,432 B
  u16* bpk = (u16*)(ws + 134217728ull);      // packed weights           337,920 B
  double* st = (double*)(ws + 134555648ull); // 7 x 128 x {sum,sumsq}     14,336 B

  hipMemsetAsync(st, 0, 14336, stream);

  WPtrs wp;
  const int widx[7] = {1, 5, 9, 13, 17, 21, 25};
  for (int i = 0; i < 7; ++i) wp.p[i] = (const float*)d_in[widx[i]];
  wpack_kernel<<<660, 256, 0, stream>>>(wp, bpk);

  quantx_kernel<<<dim3(16, 3, 128), 256, 0, stream>>>(x, xq);
  pool_kernel<<<12288, 256, 0, stream>>>(xq, xpq);

  dim3 grd(512), blk(256);

  // ---- b4 (slot 6): pooled 1x1 192->32, out 224..255 (xpq dies after) ----
  cstat_kernel<192, 1, 32><<<grd, blk, 0, stream>>>(xpq, bpk + 162816, 2, 0,
                                                    st + 6 * 256, yh);
  bnout_kernel<<<dim3(32, 32), 256, 0, stream>>>(yh, st + 6 * 256,
                                                 (const float*)d_in[27],
                                                 (const float*)d_in[28], out, 224);

  // zero padded q buffers (borders + b3a channel pad); aliases dead xpq
  hipMemsetAsync(ws + 50331648ull, 0, 47349760ull, stream);

  // ---- b1 (slot 0): 1x1 192->64, out 0..63 ----
  cstat_kernel<192, 1, 64><<<grd, blk, 0, stream>>>(xq, bpk + 0, 4, 0, st, yh);
  bnout_kernel<<<dim3(32, 64), 256, 0, stream>>>(yh, st, (const float*)d_in[3],
                                                 (const float*)d_in[4], out, 0);

  // ---- b2a (slot 1): 1x1 192->96 -> q2a ----
  cstat_kernel<192, 1, 96><<<grd, blk, 0, stream>>>(xq, bpk + 12288, 6, 0,
                                                    st + 1 * 256, yh);
  bnqpad_kernel<96, 96><<<2048, 256, 0, stream>>>(yh, st + 1 * 256,
                                                  (const float*)d_in[7],
                                                  (const float*)d_in[8], q2a);

  // ---- b2b (slot 2): 3x3 96->128, out 64..191 (two co-halves) ----
  cstat_kernel<96, 9, 64><<<grd, blk, 0, stream>>>(q2a, bpk + 30720, 8, 0,
                                                   st + 2 * 256, yh);
  cstat_kernel<96, 9, 64><<<grd, blk, 0, stream>>>(q2a, bpk + 30720, 8, 4,
                                                   st + 2 * 256 + 128,
                                                   yh + (size_t)64 * PTOT);
  bnout_kernel<<<dim3(32, 128), 256, 0, stream>>>(yh, st + 2 * 256,
                                                  (const float*)d_in[11],
                                                  (const float*)d_in[12], out, 64);

  // ---- b3a (slot 3): 1x1 192->16 -> q3a (stored as 32ch, upper 16 zero) ----
  cstat_kernel<192, 1, 16><<<grd, blk, 0, stream>>>(xq, bpk + 141312, 1, 0,
                                                    st + 3 * 256, yh);
  bnqpad_kernel<16, 32><<<2048, 256, 0, stream>>>(yh, st + 3 * 256,
                                                  (const float*)d_in[15],
                                                  (const float*)d_in[16], q3a);

  // ---- b3b (slot 4): 3x3 16->32 (CI padded to 32) -> q3b ----
  cstat_kernel<32, 9, 32><<<grd, blk, 0, stream>>>(q3a, bpk + 144384, 2, 0,
                                                   st + 4 * 256, yh);
  bnqpad_kernel<32, 32><<<2048, 256, 0, stream>>>(yh, st + 4 * 256,
                                                  (const float*)d_in[19],
                                                  (const float*)d_in[20], q3b);

  // ---- b3c (slot 5): 3x3 32->32, out 192..223 ----
  cstat_kernel<32, 9, 32><<<grd, blk, 0, stream>>>(q3b, bpk + 153600, 2, 0,
                                                   st + 5 * 256, yh);
  bnout_kernel<<<dim3(32, 32), 256, 0, stream>>>(yh, st + 5 * 256,
                                                 (const float*)d_in[23],
                                                 (const float*)d_in[24], out, 192);
}

// Round 7
// 335.718 us; speedup vs baseline: 1.4295x; 1.4295x over previous
//
#include <hip/hip_runtime.h>

typedef unsigned short u16;
typedef unsigned int u32;
typedef __attribute__((ext_vector_type(8))) short bf16x8;
typedef __attribute__((ext_vector_type(4))) float f32x4;
typedef __attribute__((ext_vector_type(4))) u16 u16x4;
typedef __attribute__((ext_vector_type(8))) u16 u16x8;

#define PTOT 131072   // 128 images * 32*32 pixels
#define NREP 16       // stat accumulator replicas (atomic de-contention)

// ---------- helpers ----------
static __device__ __forceinline__ float quantf(float v) {
  float q = rintf(v * 128.f);
  q = fmaxf(-127.f, fminf(127.f, q));
  return q * 0.0078125f;
}
static __device__ __forceinline__ u16 f2bf(float v) {   // exact for quant grid
  return (u16)(__float_as_uint(v) >> 16);
}
static __device__ __forceinline__ u16 bf_rne(float v) { // round-nearest-even bf16
  u32 u = __float_as_uint(v);
  u += 0x7fffu + ((u >> 16) & 1u);
  return (u16)(u >> 16);
}
static __device__ __forceinline__ float bf2f(u16 v) {
  return __uint_as_float((u32)v << 16);
}

// ---------- weight quantize + MFMA fragment packing (all 7 convs, 1 launch) ----------
struct WPtrs { const float* p[7]; };

__global__ void wpack_kernel(WPtrs wp, u16* __restrict__ o) {
  // {elem_off, len, CIr, CIp, KH, Co}
  static const int S[7][6] = {
      {0,      12288,  192, 192, 1, 64},  {12288,  18432,  192, 192, 1, 96},
      {30720,  110592, 96,  96,  3, 128}, {141312, 3072,   192, 192, 1, 16},
      {144384, 9216,   16,  32,  3, 32},  {153600, 9216,   32,  32,  3, 32},
      {162816, 6144,   192, 192, 1, 32},
  };
  int idx = blockIdx.x * 256 + threadIdx.x;
  if (idx >= 168960) return;
  int s = 0;
#pragma unroll
  for (int i = 1; i < 7; ++i)
    if (idx >= S[i][0]) s = i;
  int local = idx - S[s][0];
  int CIr = S[s][2], CIp = S[s][3], KH = S[s][4], Co = S[s][5];
  int j = local & 7, lane = (local >> 3) & 63, f = local >> 9;
  int NF = Co >> 4;
  int c = f / NF, nf = f - c * NF;
  int co = nf * 16 + (lane & 15);
  int k = c * 32 + ((lane >> 4) << 3) + j;
  int tap = k / CIp, ci = k - tap * CIp;
  u16 val = 0;
  if (ci < CIr) {
    int kh = tap / 3, kw = tap - kh * 3;
    val = f2bf(quantf(wp.p[s][(((size_t)co * CIr + ci) * KH + kh) * KH + kw]));
  }
  o[idx] = val;
}

// ---------- quantize x: NCHW f32 -> NHWC bf16 ----------
__global__ __launch_bounds__(256) void quantx_kernel(const float* __restrict__ x,
                                                     u16* __restrict__ xq) {
  __shared__ __align__(16) u16 tile[64][72];
  int n = blockIdx.z, hwb = blockIdx.x * 64, cb = blockIdx.y * 64;
  int lane = threadIdx.x & 63, sub = threadIdx.x >> 6;
#pragma unroll
  for (int i = 0; i < 16; ++i) {
    int c = sub + i * 4;
    float v = x[(((size_t)n * 192 + cb + c) << 10) + hwb + lane];
    tile[lane][c] = f2bf(quantf(v));
  }
  __syncthreads();
#pragma unroll
  for (int i = 0; i < 2; ++i) {
    int chunk = threadIdx.x + i * 256;
    int px = chunk >> 3, c8 = chunk & 7;
    uint4 v = *(const uint4*)&tile[px][c8 * 8];
    *(uint4*)&xq[(((size_t)n << 10) + hwb + px) * 192 + cb + c8 * 8] = v;
  }
}

// ---------- maxpool 3x3 s1 p1 on quantized NHWC bf16 ----------
__global__ __launch_bounds__(256) void pool_kernel(const u16* __restrict__ xq,
                                                   u16* __restrict__ xpq) {
  int idx = blockIdx.x * 256 + threadIdx.x;
  int c8 = idx % 24;
  int p = idx / 24;
  int n = p >> 10, hw = p & 1023, h = hw >> 5, w = hw & 31;
  float m[8];
#pragma unroll
  for (int j = 0; j < 8; ++j) m[j] = -1e30f;
  for (int dh = -1; dh <= 1; ++dh) {
    int hh = h + dh; if (hh < 0 || hh > 31) continue;
    for (int dw = -1; dw <= 1; ++dw) {
      int ww = w + dw; if (ww < 0 || ww > 31) continue;
      uint4 v = *(const uint4*)&xq[((((size_t)n << 5) + hh) * 32 + ww) * 192 + c8 * 8];
      u32 a[4] = {v.x, v.y, v.z, v.w};
#pragma unroll
      for (int t = 0; t < 4; ++t) {
        m[t * 2]     = fmaxf(m[t * 2],     __uint_as_float(a[t] << 16));
        m[t * 2 + 1] = fmaxf(m[t * 2 + 1], __uint_as_float(a[t] & 0xffff0000u));
      }
    }
  }
  uint4 o;
  u32* oa = &o.x;
#pragma unroll
  for (int t = 0; t < 4; ++t)
    oa[t] = (u32)f2bf(m[t * 2]) | ((u32)f2bf(m[t * 2 + 1]) << 16);
  *(uint4*)&xpq[(size_t)p * 192 + c8 * 8] = o;
}

// ---------- zero the 1-px borders of padded q buffers (replaces 47MB memset) ----------
__global__ __launch_bounds__(256) void border_kernel(u16* __restrict__ q2a,
                                                     u16* __restrict__ q3a,
                                                     u16* __restrict__ q3b) {
  int img = blockIdx.x, buf = blockIdx.y;
  u16* base; int C;
  if (buf == 0) { base = q2a; C = 96; }
  else if (buf == 1) { base = q3a; C = 32; }
  else { base = q3b; C = 32; }
  u16* ib = base + (size_t)img * 34 * 34 * C;
  int nch = C >> 3;  // uint4 chunks per pixel
  uint4 z = {0, 0, 0, 0};
  for (int idx = threadIdx.x; idx < 132 * nch; idx += 256) {
    int b = idx / nch, cc = idx - b * nch;
    int h, w;
    if (b < 34) { h = 0; w = b; }
    else if (b < 68) { h = 33; w = b - 34; }
    else { int s = b - 68; h = 1 + (s >> 1); w = (s & 1) ? 33 : 0; }
    *(uint4*)(ib + ((h * 34 + w) * C + cc * 8)) = z;
  }
}

// ---------- MFMA conv + bf16 y-hat write + fused per-channel stats ----------
// MF=2: wave owns 32 px x COB ch; block = 128 px; grid = PTOT/128 = 1024.
// __launch_bounds__(256,4): VGPR<=128 -> 4 waves/SIMD -> 16 waves/CU resident.
// stb: branch stat base, NREP replicas of 256 doubles; cof: channel offset.
template <int CI, int KK, int COB>
__global__ __launch_bounds__(256, 4) void cstat_kernel(
    const u16* __restrict__ xin, const u16* __restrict__ bp, int nft, int nf0,
    double* __restrict__ stb, int cof, u16* __restrict__ yh) {
  constexpr int NCH = KK * CI / 32;
  constexpr int NFW = COB / 16;
  constexpr int MF = 2;

  const int lane = threadIdx.x & 63;
  const int wave = threadIdx.x >> 6;
  const int mbase = blockIdx.x * 128 + wave * 32;

  uint abase[MF];
#pragma unroll
  for (int mf = 0; mf < MF; ++mf) {
    int p = mbase + mf * 16 + (lane & 15);
    if (KK == 1) {
      abase[mf] = (uint)p * (CI * 2);
    } else {
      int n = p >> 10, hw = p & 1023, h = hw >> 5, w = hw & 31;
      abase[mf] = (uint)((n * 34 + h) * 34 + w) * (CI * 2);
    }
  }
  const uint klane = (uint)(lane >> 4) * 16u;
  const uint blane = (uint)lane * 16u;

  f32x4 acc[MF][NFW];
#pragma unroll
  for (int i = 0; i < MF; ++i)
#pragma unroll
    for (int j = 0; j < NFW; ++j) acc[i][j] = {0.f, 0.f, 0.f, 0.f};

  auto chunk = [&](int c) {
    uint koff;
    if (KK == 1) {
      koff = (uint)c * 64u;
    } else {
      int tap = (c * 32) / CI, ci0 = (c * 32) % CI;
      koff = (uint)(((tap / 3) * 34 + (tap % 3)) * CI + ci0) * 2u;
    }
    bf16x8 af[MF];
#pragma unroll
    for (int mf = 0; mf < MF; ++mf)
      af[mf] = *(const bf16x8*)((const char*)xin + (abase[mf] + koff + klane));
    bf16x8 bfr[NFW];
#pragma unroll
    for (int nf = 0; nf < NFW; ++nf)
      bfr[nf] = *(const bf16x8*)((const char*)bp +
                                 ((uint)((c * nft + nf0 + nf) * 1024) + blane));
#pragma unroll
    for (int mf = 0; mf < MF; ++mf)
#pragma unroll
      for (int nf = 0; nf < NFW; ++nf)
        acc[mf][nf] = __builtin_amdgcn_mfma_f32_16x16x32_bf16(af[mf], bfr[nf],
                                                              acc[mf][nf], 0, 0, 0);
  };

  if (KK == 1) {
#pragma unroll
    for (int c = 0; c < NCH; ++c) chunk(c);
  } else {
#pragma unroll 2
    for (int c = 0; c < NCH; ++c) chunk(c);
  }

  // ---- write y-hat bf16 planar [co_local][PTOT] ----
#pragma unroll
  for (int mf = 0; mf < MF; ++mf)
#pragma unroll
    for (int nf = 0; nf < NFW; ++nf) {
      int col = nf * 16 + (lane & 15);
      int pix = mbase + mf * 16 + ((lane >> 4) << 2);
      u16x4 o;
#pragma unroll
      for (int r = 0; r < 4; ++r) o[r] = bf_rne(acc[mf][nf][r]);
      *(u16x4*)&yh[(size_t)col * PTOT + pix] = o;
    }

  // ---- per-channel stats over this block's 128 px -> replicated f64 atomics ----
  float s1[NFW], s2[NFW];
#pragma unroll
  for (int nf = 0; nf < NFW; ++nf) { s1[nf] = 0.f; s2[nf] = 0.f; }
#pragma unroll
  for (int mf = 0; mf < MF; ++mf)
#pragma unroll
    for (int nf = 0; nf < NFW; ++nf)
#pragma unroll
      for (int r = 0; r < 4; ++r) {
        float v = acc[mf][nf][r];
        s1[nf] += v;
        s2[nf] += v * v;
      }
#pragma unroll
  for (int m = 16; m <= 32; m <<= 1)
#pragma unroll
    for (int nf = 0; nf < NFW; ++nf) {
      s1[nf] += __shfl_xor(s1[nf], m);
      s2[nf] += __shfl_xor(s2[nf], m);
    }
  __shared__ float red[4][NFW][16][2];
  if (lane < 16)
#pragma unroll
    for (int nf = 0; nf < NFW; ++nf) {
      red[wave][nf][lane][0] = s1[nf];
      red[wave][nf][lane][1] = s2[nf];
    }
  __syncthreads();
  const int t = threadIdx.x;
  if (t < COB) {
    int nf = t >> 4, l = t & 15;
    float a = red[0][nf][l][0] + red[1][nf][l][0] + red[2][nf][l][0] + red[3][nf][l][0];
    float b = red[0][nf][l][1] + red[1][nf][l][1] + red[2][nf][l][1] + red[3][nf][l][1];
    int rep = blockIdx.x & (NREP - 1);
    atomicAdd(&stb[rep * 256 + 2 * (cof + t)], (double)a);
    atomicAdd(&stb[rep * 256 + 2 * (cof + t) + 1], (double)b);
  }
}

// ---------- BN+ReLU -> final f32 NCHW out; coefs inline from replicated stats ----------
__global__ __launch_bounds__(256) void bnout_kernel(const u16* __restrict__ yh,
                                                    const double* __restrict__ stb,
                                                    const float* __restrict__ g,
                                                    const float* __restrict__ be,
                                                    float* __restrict__ out, int cog) {
  int co = blockIdx.y, chunk = blockIdx.x, tid = threadIdx.x;
  double s1d = 0., s2d = 0.;
#pragma unroll
  for (int r = 0; r < NREP; ++r) {
    s1d += stb[r * 256 + 2 * co];
    s2d += stb[r * 256 + 2 * co + 1];
  }
  double m = s1d * (1.0 / PTOT);
  double v = s2d * (1.0 / PTOT) - m * m;
  double inv = 1.0 / sqrt(v + 1e-5);
  double c0d = (double)g[co] * inv;
  float c0 = (float)c0d;
  float c1 = (float)((double)be[co] - m * c0d);

  int p0 = chunk * 4096 + tid * 16;
  int n = p0 >> 10, hw = p0 & 1023;
  const u16* yp = yh + (size_t)co * PTOT + p0;
  float* op = out + (((size_t)(n * 256 + cog + co)) << 10) + hw;
#pragma unroll
  for (int half = 0; half < 2; ++half) {
    u16x8 r = *(const u16x8*)(yp + half * 8);
    f32x4 a, b;
#pragma unroll
    for (int e = 0; e < 4; ++e) {
      a[e] = fmaxf(fmaf(bf2f(r[e]), c0, c1), 0.f);
      b[e] = fmaxf(fmaf(bf2f(r[e + 4]), c0, c1), 0.f);
    }
    *(f32x4*)(op + half * 8) = a;
    *(f32x4*)(op + half * 8 + 4) = b;
  }
}

// ---------- BN+ReLU+quantize -> padded NHWC bf16; coefs inline ----------
template <int CO, int COP>
__global__ __launch_bounds__(256) void bnqpad_kernel(const u16* __restrict__ yh,
                                                     const double* __restrict__ stb,
                                                     const float* __restrict__ g,
                                                     const float* __restrict__ be,
                                                     u16* __restrict__ q) {
  __shared__ float2 cfl[CO];
  __shared__ __align__(16) u16 tile[64][COP + 8];
  const int t = threadIdx.x;
  if (t < CO) {
    double s1d = 0., s2d = 0.;
#pragma unroll
    for (int r = 0; r < NREP; ++r) {
      s1d += stb[r * 256 + 2 * t];
      s2d += stb[r * 256 + 2 * t + 1];
    }
    double m = s1d * (1.0 / PTOT);
    double v = s2d * (1.0 / PTOT) - m * m;
    double inv = 1.0 / sqrt(v + 1e-5);
    double c0 = (double)g[t] * inv;
    cfl[t] = make_float2((float)c0, (float)((double)be[t] - m * c0));
  }
  __syncthreads();
  int p0 = blockIdx.x * 64;
  int lane = t & 63, sub = t >> 6;
#pragma unroll
  for (int i = 0; i < COP / 4; ++i) {
    int co = sub + i * 4;
    u16 outv = 0;
    if (CO == COP || co < CO) {
      float2 cc = cfl[co];
      float yv = bf2f(yh[(size_t)co * PTOT + p0 + lane]);
      float z = fmaxf(fmaf(yv, cc.x, cc.y), 0.f);
      float qv = fminf(rintf(z * 128.f), 127.f) * 0.0078125f;  // z>=0 after relu
      outv = f2bf(qv);
    }
    tile[lane][co] = outv;
  }
  __syncthreads();
  for (int chunk = t; chunk < 64 * (COP / 8); chunk += 256) {
    int px = chunk / (COP / 8), c8 = chunk % (COP / 8);
    int p = p0 + px;
    int n = p >> 10, hw = p & 1023, h = hw >> 5, w = hw & 31;
    size_t dst = (((size_t)n * 34 + h + 1) * 34 + (w + 1)) * COP + c8 * 8;
    *(uint4*)&q[dst] = *(const uint4*)&tile[px][c8 * 8];
  }
}

extern "C" void kernel_launch(void* const* d_in, const int* in_sizes, int n_in,
                              void* d_out, int out_size, void* d_ws, size_t ws_size,
                              hipStream_t stream) {
  const float* x = (const float*)d_in[0];
  float* out = (float*)d_out;
  char* ws = (char*)d_ws;

  // ---- workspace layout (total 134,785,024 B) ----
  if (ws_size < 134785024ull) return;
  u16* xq  = (u16*)ws;                       // [PTOT][192] bf16      = 50,331,648 B
  u16* xpq = (u16*)(ws + 50331648ull);       // pooled [PTOT][192]    = 50,331,648 B
  u16* q2a = xpq;                            // reuse: [128][34][34][96]
  u16* q3a = (u16*)(ws + 78741504ull);       // reuse: [128][34][34][32]
  u16* q3b = (u16*)(ws + 88211456ull);       // reuse: [128][34][34][32]
  u16* yh  = (u16*)(ws + 100663296ull);      // [<=128][PTOT] bf16    = 33,554,432 B
  u16* bpk = (u16*)(ws + 134217728ull);      // packed weights           337,920 B
  double* st = (double*)(ws + 134555648ull); // 7 branches x NREP x 256 doubles = 229,376 B

  hipMemsetAsync(st, 0, 7 * NREP * 256 * 8, stream);

  WPtrs wp;
  const int widx[7] = {1, 5, 9, 13, 17, 21, 25};
  for (int i = 0; i < 7; ++i) wp.p[i] = (const float*)d_in[widx[i]];
  wpack_kernel<<<660, 256, 0, stream>>>(wp, bpk);

  quantx_kernel<<<dim3(16, 3, 128), 256, 0, stream>>>(x, xq);
  pool_kernel<<<12288, 256, 0, stream>>>(xq, xpq);

  dim3 grd(1024), blk(256);
  double* stB[7];
  for (int b = 0; b < 7; ++b) stB[b] = st + (size_t)b * NREP * 256;

  // ---- b4 (slot 6): pooled 1x1 192->32, out 224..255 (xpq dies after) ----
  cstat_kernel<192, 1, 32><<<grd, blk, 0, stream>>>(xpq, bpk + 162816, 2, 0,
                                                    stB[6], 0, yh);
  bnout_kernel<<<dim3(32, 32), 256, 0, stream>>>(yh, stB[6], (const float*)d_in[27],
                                                 (const float*)d_in[28], out, 224);

  // zero borders of padded q buffers (aliases dead xpq; interiors written by bnqpad)
  border_kernel<<<dim3(128, 3), 256, 0, stream>>>(q2a, q3a, q3b);

  // ---- b1 (slot 0): 1x1 192->64, out 0..63 ----
  cstat_kernel<192, 1, 64><<<grd, blk, 0, stream>>>(xq, bpk + 0, 4, 0, stB[0], 0, yh);
  bnout_kernel<<<dim3(32, 64), 256, 0, stream>>>(yh, stB[0], (const float*)d_in[3],
                                                 (const float*)d_in[4], out, 0);

  // ---- b2a (slot 1): 1x1 192->96 -> q2a (co-slices 64 + 32) ----
  cstat_kernel<192, 1, 64><<<grd, blk, 0, stream>>>(xq, bpk + 12288, 6, 0,
                                                    stB[1], 0, yh);
  cstat_kernel<192, 1, 32><<<grd, blk, 0, stream>>>(xq, bpk + 12288, 6, 4,
                                                    stB[1], 64, yh + (size_t)64 * PTOT);
  bnqpad_kernel<96, 96><<<2048, 256, 0, stream>>>(yh, stB[1], (const float*)d_in[7],
                                                  (const float*)d_in[8], q2a);

  // ---- b2b (slot 2): 3x3 96->128, out 64..191 (two co-halves) ----
  cstat_kernel<96, 9, 64><<<grd, blk, 0, stream>>>(q2a, bpk + 30720, 8, 0,
                                                   stB[2], 0, yh);
  cstat_kernel<96, 9, 64><<<grd, blk, 0, stream>>>(q2a, bpk + 30720, 8, 4,
                                                   stB[2], 64, yh + (size_t)64 * PTOT);
  bnout_kernel<<<dim3(32, 128), 256, 0, stream>>>(yh, stB[2], (const float*)d_in[11],
                                                  (const float*)d_in[12], out, 64);

  // ---- b3a (slot 3): 1x1 192->16 -> q3a (stored as 32ch, upper 16 zero) ----
  cstat_kernel<192, 1, 16><<<grd, blk, 0, stream>>>(xq, bpk + 141312, 1, 0,
                                                    stB[3], 0, yh);
  bnqpad_kernel<16, 32><<<2048, 256, 0, stream>>>(yh, stB[3], (const float*)d_in[15],
                                                  (const float*)d_in[16], q3a);

  // ---- b3b (slot 4): 3x3 16->32 (CI padded to 32) -> q3b ----
  cstat_kernel<32, 9, 32><<<grd, blk, 0, stream>>>(q3a, bpk + 144384, 2, 0,
                                                   stB[4], 0, yh);
  bnqpad_kernel<32, 32><<<2048, 256, 0, stream>>>(yh, stB[4], (const float*)d_in[19],
                                                  (const float*)d_in[20], q3b);

  // ---- b3c (slot 5): 3x3 32->32, out 192..223 ----
  cstat_kernel<32, 9, 32><<<grd, blk, 0, stream>>>(q3b, bpk + 153600, 2, 0,
                                                   stB[5], 0, yh);
  bnout_kernel<<<dim3(32, 32), 256, 0, stream>>>(yh, stB[5], (const float*)d_in[23],
                                                 (const float*)d_in[24], out, 192);
}

// Round 8
// 312.482 us; speedup vs baseline: 1.5358x; 1.0744x over previous
//
#include <hip/hip_runtime.h>

typedef unsigned short u16;
typedef unsigned int u32;
typedef __attribute__((ext_vector_type(8))) short bf16x8;
typedef __attribute__((ext_vector_type(4))) float f32x4;
typedef __attribute__((ext_vector_type(4))) u16 u16x4;
typedef __attribute__((ext_vector_type(8))) u16 u16x8;

#define PTOT 131072   // 128 images * 32*32 pixels
#define NREP 16       // stat accumulator replicas (atomic de-contention)

// ---------- helpers ----------
static __device__ __forceinline__ float quantf(float v) {
  float q = rintf(v * 128.f);
  q = fmaxf(-127.f, fminf(127.f, q));
  return q * 0.0078125f;
}
static __device__ __forceinline__ u16 f2bf(float v) {   // exact for quant grid
  return (u16)(__float_as_uint(v) >> 16);
}
static __device__ __forceinline__ u16 bf_rne(float v) { // round-nearest-even bf16
  u32 u = __float_as_uint(v);
  u += 0x7fffu + ((u >> 16) & 1u);
  return (u16)(u >> 16);
}
static __device__ __forceinline__ float bf2f(u16 v) {
  return __uint_as_float((u32)v << 16);
}

// ---------- weight quantize + MFMA fragment packing (all 7 convs, 1 launch) ----------
struct WPtrs { const float* p[7]; };

__global__ void wpack_kernel(WPtrs wp, u16* __restrict__ o) {
  // {elem_off, len, CIr, CIp, KH, Co}
  static const int S[7][6] = {
      {0,      12288,  192, 192, 1, 64},  {12288,  18432,  192, 192, 1, 96},
      {30720,  110592, 96,  96,  3, 128}, {141312, 3072,   192, 192, 1, 16},
      {144384, 9216,   16,  32,  3, 32},  {153600, 9216,   32,  32,  3, 32},
      {162816, 6144,   192, 192, 1, 32},
  };
  int idx = blockIdx.x * 256 + threadIdx.x;
  if (idx >= 168960) return;
  int s = 0;
#pragma unroll
  for (int i = 1; i < 7; ++i)
    if (idx >= S[i][0]) s = i;
  int local = idx - S[s][0];
  int CIr = S[s][2], CIp = S[s][3], KH = S[s][4], Co = S[s][5];
  int j = local & 7, lane = (local >> 3) & 63, f = local >> 9;
  int NF = Co >> 4;
  int c = f / NF, nf = f - c * NF;
  int co = nf * 16 + (lane & 15);
  int k = c * 32 + ((lane >> 4) << 3) + j;
  int tap = k / CIp, ci = k - tap * CIp;
  u16 val = 0;
  if (ci < CIr) {
    int kh = tap / 3, kw = tap - kh * 3;
    val = f2bf(quantf(wp.p[s][(((size_t)co * CIr + ci) * KH + kh) * KH + kw]));
  }
  o[idx] = val;
}

// ---------- quantize x: NCHW f32 -> NHWC bf16 ----------
__global__ __launch_bounds__(256) void quantx_kernel(const float* __restrict__ x,
                                                     u16* __restrict__ xq) {
  __shared__ __align__(16) u16 tile[64][72];
  int n = blockIdx.z, hwb = blockIdx.x * 64, cb = blockIdx.y * 64;
  int lane = threadIdx.x & 63, sub = threadIdx.x >> 6;
#pragma unroll
  for (int i = 0; i < 16; ++i) {
    int c = sub + i * 4;
    float v = x[(((size_t)n * 192 + cb + c) << 10) + hwb + lane];
    tile[lane][c] = f2bf(quantf(v));
  }
  __syncthreads();
#pragma unroll
  for (int i = 0; i < 2; ++i) {
    int chunk = threadIdx.x + i * 256;
    int px = chunk >> 3, c8 = chunk & 7;
    uint4 v = *(const uint4*)&tile[px][c8 * 8];
    *(uint4*)&xq[(((size_t)n << 10) + hwb + px) * 192 + cb + c8 * 8] = v;
  }
}

// ---------- maxpool 3x3 s1 p1 on quantized NHWC bf16 ----------
__global__ __launch_bounds__(256) void pool_kernel(const u16* __restrict__ xq,
                                                   u16* __restrict__ xpq) {
  int idx = blockIdx.x * 256 + threadIdx.x;
  int c8 = idx % 24;
  int p = idx / 24;
  int n = p >> 10, hw = p & 1023, h = hw >> 5, w = hw & 31;
  float m[8];
#pragma unroll
  for (int j = 0; j < 8; ++j) m[j] = -1e30f;
  for (int dh = -1; dh <= 1; ++dh) {
    int hh = h + dh; if (hh < 0 || hh > 31) continue;
    for (int dw = -1; dw <= 1; ++dw) {
      int ww = w + dw; if (ww < 0 || ww > 31) continue;
      uint4 v = *(const uint4*)&xq[((((size_t)n << 5) + hh) * 32 + ww) * 192 + c8 * 8];
      u32 a[4] = {v.x, v.y, v.z, v.w};
#pragma unroll
      for (int t = 0; t < 4; ++t) {
        m[t * 2]     = fmaxf(m[t * 2],     __uint_as_float(a[t] << 16));
        m[t * 2 + 1] = fmaxf(m[t * 2 + 1], __uint_as_float(a[t] & 0xffff0000u));
      }
    }
  }
  uint4 o;
  u32* oa = &o.x;
#pragma unroll
  for (int t = 0; t < 4; ++t)
    oa[t] = (u32)f2bf(m[t * 2]) | ((u32)f2bf(m[t * 2 + 1]) << 16);
  *(uint4*)&xpq[(size_t)p * 192 + c8 * 8] = o;
}

// ---------- zero the 1-px borders of padded q buffers ----------
__global__ __launch_bounds__(256) void border_kernel(u16* __restrict__ q2a,
                                                     u16* __restrict__ q3a,
                                                     u16* __restrict__ q3b) {
  int img = blockIdx.x, buf = blockIdx.y;
  u16* base; int C;
  if (buf == 0) { base = q2a; C = 96; }
  else if (buf == 1) { base = q3a; C = 32; }
  else { base = q3b; C = 32; }
  u16* ib = base + (size_t)img * 34 * 34 * C;
  int nch = C >> 3;
  uint4 z = {0, 0, 0, 0};
  for (int idx = threadIdx.x; idx < 132 * nch; idx += 256) {
    int b = idx / nch, cc = idx - b * nch;
    int h, w;
    if (b < 34) { h = 0; w = b; }
    else if (b < 68) { h = 33; w = b - 34; }
    else { int s = b - 68; h = 1 + (s >> 1); w = (s & 1) ? 33 : 0; }
    *(uint4*)(ib + ((h * 34 + w) * C + cc * 8)) = z;
  }
}

// ---------- MFMA conv + bf16 y-hat write + fused per-channel stats ----------
// MF=2: wave owns 32 px x COB ch; block = 128 px; grid = PTOT/128 = 1024.
// WPEU: min waves per SIMD (VGPR cap). NFW<=6 -> 4 (128 VGPR); NFW=8 -> 3 (170).
template <int CI, int KK, int COB, int WPEU>
__global__ __launch_bounds__(256, WPEU) void cstat_kernel(
    const u16* __restrict__ xin, const u16* __restrict__ bp, int nft, int nf0,
    double* __restrict__ stb, int cof, u16* __restrict__ yh) {
  constexpr int NCH = KK * CI / 32;
  constexpr int NFW = COB / 16;
  constexpr int MF = 2;

  const int lane = threadIdx.x & 63;
  const int wave = threadIdx.x >> 6;
  const int mbase = blockIdx.x * 128 + wave * 32;

  uint abase[MF];
#pragma unroll
  for (int mf = 0; mf < MF; ++mf) {
    int p = mbase + mf * 16 + (lane & 15);
    if (KK == 1) {
      abase[mf] = (uint)p * (CI * 2);
    } else {
      int n = p >> 10, hw = p & 1023, h = hw >> 5, w = hw & 31;
      abase[mf] = (uint)((n * 34 + h) * 34 + w) * (CI * 2);
    }
  }
  const uint klane = (uint)(lane >> 4) * 16u;
  const uint blane = (uint)lane * 16u;

  f32x4 acc[MF][NFW];
#pragma unroll
  for (int i = 0; i < MF; ++i)
#pragma unroll
    for (int j = 0; j < NFW; ++j) acc[i][j] = {0.f, 0.f, 0.f, 0.f};

  auto chunk = [&](int c) {
    uint koff;
    if (KK == 1) {
      koff = (uint)c * 64u;
    } else {
      int tap = (c * 32) / CI, ci0 = (c * 32) % CI;
      koff = (uint)(((tap / 3) * 34 + (tap % 3)) * CI + ci0) * 2u;
    }
    bf16x8 af[MF];
#pragma unroll
    for (int mf = 0; mf < MF; ++mf)
      af[mf] = *(const bf16x8*)((const char*)xin + (abase[mf] + koff + klane));
    bf16x8 bfr[NFW];
#pragma unroll
    for (int nf = 0; nf < NFW; ++nf)
      bfr[nf] = *(const bf16x8*)((const char*)bp +
                                 ((uint)((c * nft + nf0 + nf) * 1024) + blane));
#pragma unroll
    for (int mf = 0; mf < MF; ++mf)
#pragma unroll
      for (int nf = 0; nf < NFW; ++nf)
        acc[mf][nf] = __builtin_amdgcn_mfma_f32_16x16x32_bf16(af[mf], bfr[nf],
                                                              acc[mf][nf], 0, 0, 0);
  };

  if (KK == 1) {
#pragma unroll
    for (int c = 0; c < NCH; ++c) chunk(c);
  } else {
#pragma unroll 3
    for (int c = 0; c < NCH; ++c) chunk(c);
  }

  // ---- write y-hat bf16 planar [co_local][PTOT] ----
#pragma unroll
  for (int mf = 0; mf < MF; ++mf)
#pragma unroll
    for (int nf = 0; nf < NFW; ++nf) {
      int col = nf * 16 + (lane & 15);
      int pix = mbase + mf * 16 + ((lane >> 4) << 2);
      u16x4 o;
#pragma unroll
      for (int r = 0; r < 4; ++r) o[r] = bf_rne(acc[mf][nf][r]);
      *(u16x4*)&yh[(size_t)col * PTOT + pix] = o;
    }

  // ---- per-channel stats over this block's 128 px -> replicated f64 atomics ----
  float s1[NFW], s2[NFW];
#pragma unroll
  for (int nf = 0; nf < NFW; ++nf) { s1[nf] = 0.f; s2[nf] = 0.f; }
#pragma unroll
  for (int mf = 0; mf < MF; ++mf)
#pragma unroll
    for (int nf = 0; nf < NFW; ++nf)
#pragma unroll
      for (int r = 0; r < 4; ++r) {
        float v = acc[mf][nf][r];
        s1[nf] += v;
        s2[nf] += v * v;
      }
#pragma unroll
  for (int m = 16; m <= 32; m <<= 1)
#pragma unroll
    for (int nf = 0; nf < NFW; ++nf) {
      s1[nf] += __shfl_xor(s1[nf], m);
      s2[nf] += __shfl_xor(s2[nf], m);
    }
  __shared__ float red[4][NFW][16][2];
  if (lane < 16)
#pragma unroll
    for (int nf = 0; nf < NFW; ++nf) {
      red[wave][nf][lane][0] = s1[nf];
      red[wave][nf][lane][1] = s2[nf];
    }
  __syncthreads();
  const int t = threadIdx.x;
  if (t < COB) {
    int nf = t >> 4, l = t & 15;
    float a = red[0][nf][l][0] + red[1][nf][l][0] + red[2][nf][l][0] + red[3][nf][l][0];
    float b = red[0][nf][l][1] + red[1][nf][l][1] + red[2][nf][l][1] + red[3][nf][l][1];
    int rep = blockIdx.x & (NREP - 1);
    atomicAdd(&stb[rep * 256 + 2 * (cof + t)], (double)a);
    atomicAdd(&stb[rep * 256 + 2 * (cof + t) + 1], (double)b);
  }
}

// ---------- BN+ReLU -> final f32 NCHW out; coefs inline from replicated stats ----------
__global__ __launch_bounds__(256) void bnout_kernel(const u16* __restrict__ yh,
                                                    const double* __restrict__ stb,
                                                    const float* __restrict__ g,
                                                    const float* __restrict__ be,
                                                    float* __restrict__ out, int cog) {
  int co = blockIdx.y, chunk = blockIdx.x, tid = threadIdx.x;
  double s1d = 0., s2d = 0.;
#pragma unroll
  for (int r = 0; r < NREP; ++r) {
    s1d += stb[r * 256 + 2 * co];
    s2d += stb[r * 256 + 2 * co + 1];
  }
  double m = s1d * (1.0 / PTOT);
  double v = s2d * (1.0 / PTOT) - m * m;
  double inv = 1.0 / sqrt(v + 1e-5);
  double c0d = (double)g[co] * inv;
  float c0 = (float)c0d;
  float c1 = (float)((double)be[co] - m * c0d);

  int p0 = chunk * 4096 + tid * 16;
  int n = p0 >> 10, hw = p0 & 1023;
  const u16* yp = yh + (size_t)co * PTOT + p0;
  float* op = out + (((size_t)(n * 256 + cog + co)) << 10) + hw;
#pragma unroll
  for (int half = 0; half < 2; ++half) {
    u16x8 r = *(const u16x8*)(yp + half * 8);
    f32x4 a, b;
#pragma unroll
    for (int e = 0; e < 4; ++e) {
      a[e] = fmaxf(fmaf(bf2f(r[e]), c0, c1), 0.f);
      b[e] = fmaxf(fmaf(bf2f(r[e + 4]), c0, c1), 0.f);
    }
    *(f32x4*)(op + half * 8) = a;
    *(f32x4*)(op + half * 8 + 4) = b;
  }
}

// ---------- BN+ReLU+quantize -> padded NHWC bf16; coefs inline ----------
template <int CO, int COP>
__global__ __launch_bounds__(256) void bnqpad_kernel(const u16* __restrict__ yh,
                                                     const double* __restrict__ stb,
                                                     const float* __restrict__ g,
                                                     const float* __restrict__ be,
                                                     u16* __restrict__ q) {
  __shared__ float2 cfl[CO];
  __shared__ __align__(16) u16 tile[64][COP + 8];
  const int t = threadIdx.x;
  if (t < CO) {
    double s1d = 0., s2d = 0.;
#pragma unroll
    for (int r = 0; r < NREP; ++r) {
      s1d += stb[r * 256 + 2 * t];
      s2d += stb[r * 256 + 2 * t + 1];
    }
    double m = s1d * (1.0 / PTOT);
    double v = s2d * (1.0 / PTOT) - m * m;
    double inv = 1.0 / sqrt(v + 1e-5);
    double c0 = (double)g[t] * inv;
    cfl[t] = make_float2((float)c0, (float)((double)be[t] - m * c0));
  }
  __syncthreads();
  int p0 = blockIdx.x * 64;
  int lane = t & 63, sub = t >> 6;
#pragma unroll
  for (int i = 0; i < COP / 4; ++i) {
    int co = sub + i * 4;
    u16 outv = 0;
    if (CO == COP || co < CO) {
      float2 cc = cfl[co];
      float yv = bf2f(yh[(size_t)co * PTOT + p0 + lane]);
      float z = fmaxf(fmaf(yv, cc.x, cc.y), 0.f);
      float qv = fminf(rintf(z * 128.f), 127.f) * 0.0078125f;  // z>=0 after relu
      outv = f2bf(qv);
    }
    tile[lane][co] = outv;
  }
  __syncthreads();
  for (int chunk = t; chunk < 64 * (COP / 8); chunk += 256) {
    int px = chunk / (COP / 8), c8 = chunk % (COP / 8);
    int p = p0 + px;
    int n = p >> 10, hw = p & 1023, h = hw >> 5, w = hw & 31;
    size_t dst = (((size_t)n * 34 + h + 1) * 34 + (w + 1)) * COP + c8 * 8;
    *(uint4*)&q[dst] = *(const uint4*)&tile[px][c8 * 8];
  }
}

extern "C" void kernel_launch(void* const* d_in, const int* in_sizes, int n_in,
                              void* d_out, int out_size, void* d_ws, size_t ws_size,
                              hipStream_t stream) {
  const float* x = (const float*)d_in[0];
  float* out = (float*)d_out;
  char* ws = (char*)d_ws;

  // ---- workspace layout (total 134,785,024 B) ----
  if (ws_size < 134785024ull) return;
  u16* xq  = (u16*)ws;                       // [PTOT][192] bf16      = 50,331,648 B
  u16* xpq = (u16*)(ws + 50331648ull);       // pooled [PTOT][192]    = 50,331,648 B
  u16* q2a = xpq;                            // reuse: [128][34][34][96]
  u16* q3a = (u16*)(ws + 78741504ull);       // reuse: [128][34][34][32]
  u16* q3b = (u16*)(ws + 88211456ull);       // reuse: [128][34][34][32]
  u16* yh  = (u16*)(ws + 100663296ull);      // [<=128][PTOT] bf16    = 33,554,432 B
  u16* bpk = (u16*)(ws + 134217728ull);      // packed weights           337,920 B
  double* st = (double*)(ws + 134555648ull); // 7 branches x NREP x 256 doubles

  hipMemsetAsync(st, 0, 7 * NREP * 256 * 8, stream);

  WPtrs wp;
  const int widx[7] = {1, 5, 9, 13, 17, 21, 25};
  for (int i = 0; i < 7; ++i) wp.p[i] = (const float*)d_in[widx[i]];
  wpack_kernel<<<660, 256, 0, stream>>>(wp, bpk);

  quantx_kernel<<<dim3(16, 3, 128), 256, 0, stream>>>(x, xq);
  pool_kernel<<<12288, 256, 0, stream>>>(xq, xpq);

  dim3 grd(1024), blk(256);
  double* stB[7];
  for (int b = 0; b < 7; ++b) stB[b] = st + (size_t)b * NREP * 256;

  // ---- b4 (slot 6): pooled 1x1 192->32, out 224..255 (xpq dies after) ----
  cstat_kernel<192, 1, 32, 4><<<grd, blk, 0, stream>>>(xpq, bpk + 162816, 2, 0,
                                                       stB[6], 0, yh);
  bnout_kernel<<<dim3(32, 32), 256, 0, stream>>>(yh, stB[6], (const float*)d_in[27],
                                                 (const float*)d_in[28], out, 224);

  // zero borders of padded q buffers (aliases dead xpq)
  border_kernel<<<dim3(128, 3), 256, 0, stream>>>(q2a, q3a, q3b);

  // ---- b1 (slot 0): 1x1 192->64, out 0..63 ----
  cstat_kernel<192, 1, 64, 4><<<grd, blk, 0, stream>>>(xq, bpk + 0, 4, 0, stB[0], 0, yh);
  bnout_kernel<<<dim3(32, 64), 256, 0, stream>>>(yh, stB[0], (const float*)d_in[3],
                                                 (const float*)d_in[4], out, 0);

  // ---- b2a (slot 1): 1x1 192->96 -> q2a (single 96-ch launch) ----
  cstat_kernel<192, 1, 96, 4><<<grd, blk, 0, stream>>>(xq, bpk + 12288, 6, 0,
                                                       stB[1], 0, yh);
  bnqpad_kernel<96, 96><<<2048, 256, 0, stream>>>(yh, stB[1], (const float*)d_in[7],
                                                  (const float*)d_in[8], q2a);

  // ---- b2b (slot 2): 3x3 96->128, out 64..191 (single 128-ch launch, WPEU=3) ----
  cstat_kernel<96, 9, 128, 3><<<grd, blk, 0, stream>>>(q2a, bpk + 30720, 8, 0,
                                                       stB[2], 0, yh);
  bnout_kernel<<<dim3(32, 128), 256, 0, stream>>>(yh, stB[2], (const float*)d_in[11],
                                                  (const float*)d_in[12], out, 64);

  // ---- b3a (slot 3): 1x1 192->16 -> q3a (stored as 32ch, upper 16 zero) ----
  cstat_kernel<192, 1, 16, 4><<<grd, blk, 0, stream>>>(xq, bpk + 141312, 1, 0,
                                                       stB[3], 0, yh);
  bnqpad_kernel<16, 32><<<2048, 256, 0, stream>>>(yh, stB[3], (const float*)d_in[15],
                                                  (const float*)d_in[16], q3a);

  // ---- b3b (slot 4): 3x3 16->32 (CI padded to 32) -> q3b ----
  cstat_kernel<32, 9, 32, 4><<<grd, blk, 0, stream>>>(q3a, bpk + 144384, 2, 0,
                                                      stB[4], 0, yh);
  bnqpad_kernel<32, 32><<<2048, 256, 0, stream>>>(yh, stB[4], (const float*)d_in[19],
                                                  (const float*)d_in[20], q3b);

  // ---- b3c (slot 5): 3x3 32->32, out 192..223 ----
  cstat_kernel<32, 9, 32, 4><<<grd, blk, 0, stream>>>(q3b, bpk + 153600, 2, 0,
                                                      stB[5], 0, yh);
  bnout_kernel<<<dim3(32, 32), 256, 0, stream>>>(yh, stB[5], (const float*)d_in[23],
                                                 (const float*)d_in[24], out, 192);
}

// Round 9
// 271.399 us; speedup vs baseline: 1.7683x; 1.1514x over previous
//
#include <hip/hip_runtime.h>

typedef unsigned short u16;
typedef unsigned int u32;
typedef __attribute__((ext_vector_type(4))) int i32x4;
typedef __attribute__((ext_vector_type(4))) float f32x4;
typedef __attribute__((ext_vector_type(4))) u16 u16x4;
typedef __attribute__((ext_vector_type(8))) u16 u16x8;

#define PTOT 131072   // 128 images * 32*32 pixels
#define NREP 16       // stat accumulator replicas (atomic de-contention)

// ---------- helpers ----------
static __device__ __forceinline__ int qi8(float v) {  // round-half-even, clip +-127
  int q = (int)rintf(v * 128.f);
  return max(-127, min(127, q));
}
static __device__ __forceinline__ u16 bf_rne(float v) { // round-nearest-even bf16
  u32 u = __float_as_uint(v);
  u += 0x7fffu + ((u >> 16) & 1u);
  return (u16)(u >> 16);
}
static __device__ __forceinline__ float bf2f(u16 v) {
  return __uint_as_float((u32)v << 16);
}

// ---------- weight quantize + i8 MFMA fragment packing (all 7 convs) ----------
// packed bytes: [NCH][NF][64 lanes][16]; co = nf*16+(lane&15),
// k = c*64 + (lane>>4)*16 + j over PADDED CIp; zero where ci >= CIr.
struct WPtrs { const float* p[7]; };

__global__ void wpack_kernel(WPtrs wp, char* __restrict__ o) {
  // {byte_off, len, CIr, CIp, KH, Co}
  static const int S[7][6] = {
      {0,      12288,  192, 192, 1, 64},  {12288,  18432,  192, 192, 1, 96},
      {30720,  147456, 96,  128, 3, 128}, {178176, 3072,   192, 192, 1, 16},
      {181248, 18432,  16,  64,  3, 32},  {199680, 18432,  32,  64,  3, 32},
      {218112, 6144,   192, 192, 1, 32},
  };
  int idx = blockIdx.x * 256 + threadIdx.x;
  if (idx >= 224256) return;
  int s = 0;
#pragma unroll
  for (int i = 1; i < 7; ++i)
    if (idx >= S[i][0]) s = i;
  int local = idx - S[s][0];
  int CIr = S[s][2], CIp = S[s][3], KH = S[s][4], Co = S[s][5];
  int j = local & 15, lane = (local >> 4) & 63, f = local >> 10;
  int NF = Co >> 4;
  int c = f / NF, nf = f - c * NF;
  int co = nf * 16 + (lane & 15);
  int k = c * 64 + ((lane >> 4) << 4) + j;
  int tap = k / CIp, ci = k - tap * CIp;
  char val = 0;
  if (ci < CIr) {
    int kh = tap / 3, kw = tap - kh * 3;
    val = (char)qi8(wp.p[s][(((size_t)co * CIr + ci) * KH + kh) * KH + kw]);
  }
  o[idx] = val;
}

// ---------- quantize x: NCHW f32 -> NHWC int8 ----------
__global__ __launch_bounds__(256) void quantx_kernel(const float* __restrict__ x,
                                                     char* __restrict__ xq) {
  __shared__ __align__(16) char tile[64][80];  // 64 px x 64 ch (+16B pad)
  int n = blockIdx.z, hwb = blockIdx.x * 64, cb = blockIdx.y * 64;
  int lane = threadIdx.x & 63, sub = threadIdx.x >> 6;
#pragma unroll
  for (int i = 0; i < 16; ++i) {
    int c = sub + i * 4;
    float v = x[(((size_t)n * 192 + cb + c) << 10) + hwb + lane];
    tile[lane][c] = (char)qi8(v);
  }
  __syncthreads();
  int t = threadIdx.x, px = t >> 2, c16 = t & 3;
  uint4 v = *(const uint4*)&tile[px][c16 * 16];
  *(uint4*)&xq[(((size_t)n << 10) + hwb + px) * 192 + cb + c16 * 16] = v;
}

// ---------- maxpool 3x3 s1 p1 on int8 NHWC (max commutes with quantize) ----------
__global__ __launch_bounds__(256) void pool_kernel(const char* __restrict__ xq,
                                                   char* __restrict__ xpq) {
  int idx = blockIdx.x * 256 + threadIdx.x;
  int c16 = idx % 12;  // 192 ch / 16
  int p = idx / 12;
  int n = p >> 10, hw = p & 1023, h = hw >> 5, w = hw & 31;
  int m[16];
#pragma unroll
  for (int j = 0; j < 16; ++j) m[j] = -127;
  for (int dh = -1; dh <= 1; ++dh) {
    int hh = h + dh; if (hh < 0 || hh > 31) continue;
    for (int dw = -1; dw <= 1; ++dw) {
      int ww = w + dw; if (ww < 0 || ww > 31) continue;
      uint4 v = *(const uint4*)&xq[((((size_t)n << 5) + hh) * 32 + ww) * 192 + c16 * 16];
      const char* bb = reinterpret_cast<const char*>(&v);
#pragma unroll
      for (int t = 0; t < 16; ++t) {
        int b = (int)bb[t];
        m[t] = b > m[t] ? b : m[t];
      }
    }
  }
  uint4 o;
  char* ob = reinterpret_cast<char*>(&o);
#pragma unroll
  for (int t = 0; t < 16; ++t) ob[t] = (char)m[t];
  *(uint4*)&xpq[(size_t)p * 192 + c16 * 16] = o;
}

// ---------- zero the 1-px borders of padded q buffers ----------
__global__ __launch_bounds__(256) void border_kernel(char* __restrict__ q2a,
                                                     char* __restrict__ q3a,
                                                     char* __restrict__ q3b) {
  int img = blockIdx.x, buf = blockIdx.y;
  char* base; int C;
  if (buf == 0) { base = q2a; C = 128; }
  else if (buf == 1) { base = q3a; C = 64; }
  else { base = q3b; C = 64; }
  char* ib = base + (size_t)img * 34 * 34 * C;
  int nch = C >> 4;  // uint4 chunks per pixel
  uint4 z = {0, 0, 0, 0};
  for (int idx = threadIdx.x; idx < 132 * nch; idx += 256) {
    int b = idx / nch, cc = idx - b * nch;
    int h, w;
    if (b < 34) { h = 0; w = b; }
    else if (b < 68) { h = 33; w = b - 34; }
    else { int s = b - 68; h = 1 + (s >> 1); w = (s & 1) ? 33 : 0; }
    *(uint4*)(ib + ((h * 34 + w) * C + cc * 16)) = z;
  }
}

// ---------- i8 MFMA conv + bf16 y-hat write + fused per-channel stats ----------
// xin i8: KK==1: [PTOT][CI]; KK==9: [128][34][34][CI] zero-padded (CI = CIp).
// y = acc_i32 * 2^-14, exact in f32 (|acc| < 2^24).
// MF=2: wave owns 32 px x COB ch; block = 128 px; grid = 1024.
template <int CI, int KK, int COB, int WPEU>
__global__ __launch_bounds__(256, WPEU) void cstat_kernel(
    const char* __restrict__ xin, const char* __restrict__ bp, int nft, int nf0,
    double* __restrict__ stb, int cof, u16* __restrict__ yh) {
  constexpr int NCH = KK * CI / 64;
  constexpr int NFW = COB / 16;
  constexpr int MF = 2;

  const int lane = threadIdx.x & 63;
  const int wave = threadIdx.x >> 6;
  const int mbase = blockIdx.x * 128 + wave * 32;

  uint abase[MF];
#pragma unroll
  for (int mf = 0; mf < MF; ++mf) {
    int p = mbase + mf * 16 + (lane & 15);
    if (KK == 1) {
      abase[mf] = (uint)p * CI;
    } else {
      int n = p >> 10, hw = p & 1023, h = hw >> 5, w = hw & 31;
      abase[mf] = (uint)((n * 34 + h) * 34 + w) * CI;
    }
  }
  const uint klane = (uint)(lane >> 4) * 16u;  // k-subgroup byte offset (16 i8)
  const uint blane = (uint)lane * 16u;

  i32x4 acc[MF][NFW];
#pragma unroll
  for (int i = 0; i < MF; ++i)
#pragma unroll
    for (int j = 0; j < NFW; ++j) acc[i][j] = {0, 0, 0, 0};

  auto chunk = [&](int c) {
    uint koff;
    if (KK == 1) {
      koff = (uint)c * 64u;
    } else {
      int tap = (c * 64) / CI, ci0 = (c * 64) % CI;  // (3*CI)%64==0: no row straddle
      koff = (uint)(((tap / 3) * 34 + (tap % 3)) * CI + ci0);
    }
    i32x4 af[MF];
#pragma unroll
    for (int mf = 0; mf < MF; ++mf)
      af[mf] = *(const i32x4*)(xin + (abase[mf] + koff + klane));
    i32x4 bfr[NFW];
#pragma unroll
    for (int nf = 0; nf < NFW; ++nf)
      bfr[nf] = *(const i32x4*)(bp + ((uint)((c * nft + nf0 + nf) * 1024) + blane));
#pragma unroll
    for (int mf = 0; mf < MF; ++mf)
#pragma unroll
      for (int nf = 0; nf < NFW; ++nf)
        acc[mf][nf] = __builtin_amdgcn_mfma_i32_16x16x64_i8(af[mf], bfr[nf],
                                                            acc[mf][nf], 0, 0, 0);
  };

  if (KK == 1) {
#pragma unroll
    for (int c = 0; c < NCH; ++c) chunk(c);
  } else {
#pragma unroll 3
    for (int c = 0; c < NCH; ++c) chunk(c);
  }

  // ---- convert to float y (exact), write y-hat bf16 planar [co_local][PTOT] ----
  float yv[MF][NFW][4];
#pragma unroll
  for (int mf = 0; mf < MF; ++mf)
#pragma unroll
    for (int nf = 0; nf < NFW; ++nf) {
      int col = nf * 16 + (lane & 15);
      int pix = mbase + mf * 16 + ((lane >> 4) << 2);
      u16x4 o;
#pragma unroll
      for (int r = 0; r < 4; ++r) {
        float v = (float)acc[mf][nf][r] * 6.103515625e-05f;  // 2^-14
        yv[mf][nf][r] = v;
        o[r] = bf_rne(v);
      }
      *(u16x4*)&yh[(size_t)col * PTOT + pix] = o;
    }

  // ---- per-channel stats over this block's 128 px -> replicated f64 atomics ----
  float s1[NFW], s2[NFW];
#pragma unroll
  for (int nf = 0; nf < NFW; ++nf) { s1[nf] = 0.f; s2[nf] = 0.f; }
#pragma unroll
  for (int mf = 0; mf < MF; ++mf)
#pragma unroll
    for (int nf = 0; nf < NFW; ++nf)
#pragma unroll
      for (int r = 0; r < 4; ++r) {
        float v = yv[mf][nf][r];
        s1[nf] += v;
        s2[nf] += v * v;
      }
#pragma unroll
  for (int m = 16; m <= 32; m <<= 1)
#pragma unroll
    for (int nf = 0; nf < NFW; ++nf) {
      s1[nf] += __shfl_xor(s1[nf], m);
      s2[nf] += __shfl_xor(s2[nf], m);
    }
  __shared__ float red[4][NFW][16][2];
  if (lane < 16)
#pragma unroll
    for (int nf = 0; nf < NFW; ++nf) {
      red[wave][nf][lane][0] = s1[nf];
      red[wave][nf][lane][1] = s2[nf];
    }
  __syncthreads();
  const int t = threadIdx.x;
  if (t < COB) {
    int nf = t >> 4, l = t & 15;
    float a = red[0][nf][l][0] + red[1][nf][l][0] + red[2][nf][l][0] + red[3][nf][l][0];
    float b = red[0][nf][l][1] + red[1][nf][l][1] + red[2][nf][l][1] + red[3][nf][l][1];
    int rep = blockIdx.x & (NREP - 1);
    atomicAdd(&stb[rep * 256 + 2 * (cof + t)], (double)a);
    atomicAdd(&stb[rep * 256 + 2 * (cof + t) + 1], (double)b);
  }
}

// ---------- BN+ReLU -> final f32 NCHW out; coefs inline from replicated stats ----------
__global__ __launch_bounds__(256) void bnout_kernel(const u16* __restrict__ yh,
                                                    const double* __restrict__ stb,
                                                    const float* __restrict__ g,
                                                    const float* __restrict__ be,
                                                    float* __restrict__ out, int cog) {
  int co = blockIdx.y, chunk = blockIdx.x, tid = threadIdx.x;
  double s1d = 0., s2d = 0.;
#pragma unroll
  for (int r = 0; r < NREP; ++r) {
    s1d += stb[r * 256 + 2 * co];
    s2d += stb[r * 256 + 2 * co + 1];
  }
  double m = s1d * (1.0 / PTOT);
  double v = s2d * (1.0 / PTOT) - m * m;
  double inv = 1.0 / sqrt(v + 1e-5);
  double c0d = (double)g[co] * inv;
  float c0 = (float)c0d;
  float c1 = (float)((double)be[co] - m * c0d);

  int p0 = chunk * 4096 + tid * 16;
  int n = p0 >> 10, hw = p0 & 1023;
  const u16* yp = yh + (size_t)co * PTOT + p0;
  float* op = out + (((size_t)(n * 256 + cog + co)) << 10) + hw;
#pragma unroll
  for (int half = 0; half < 2; ++half) {
    u16x8 r = *(const u16x8*)(yp + half * 8);
    f32x4 a, b;
#pragma unroll
    for (int e = 0; e < 4; ++e) {
      a[e] = fmaxf(fmaf(bf2f(r[e]), c0, c1), 0.f);
      b[e] = fmaxf(fmaf(bf2f(r[e + 4]), c0, c1), 0.f);
    }
    *(f32x4*)(op + half * 8) = a;
    *(f32x4*)(op + half * 8 + 4) = b;
  }
}

// ---------- BN+ReLU+quantize -> padded NHWC int8; coefs inline ----------
template <int CO, int COP>
__global__ __launch_bounds__(256) void bnqpad_kernel(const u16* __restrict__ yh,
                                                     const double* __restrict__ stb,
                                                     const float* __restrict__ g,
                                                     const float* __restrict__ be,
                                                     char* __restrict__ q) {
  __shared__ float2 cfl[CO];
  __shared__ __align__(16) char tile[64][COP + 16];
  const int t = threadIdx.x;
  if (t < CO) {
    double s1d = 0., s2d = 0.;
#pragma unroll
    for (int r = 0; r < NREP; ++r) {
      s1d += stb[r * 256 + 2 * t];
      s2d += stb[r * 256 + 2 * t + 1];
    }
    double m = s1d * (1.0 / PTOT);
    double v = s2d * (1.0 / PTOT) - m * m;
    double inv = 1.0 / sqrt(v + 1e-5);
    double c0 = (double)g[t] * inv;
    cfl[t] = make_float2((float)c0, (float)((double)be[t] - m * c0));
  }
  __syncthreads();
  int p0 = blockIdx.x * 64;
  int lane = t & 63, sub = t >> 6;
#pragma unroll
  for (int i = 0; i < COP / 4; ++i) {
    int co = sub + i * 4;
    char outv = 0;
    if (CO == COP || co < CO) {
      float2 cc = cfl[co];
      float z = fmaxf(fmaf(bf2f(yh[(size_t)co * PTOT + p0 + lane]), cc.x, cc.y), 0.f);
      outv = (char)min((int)rintf(z * 128.f), 127);  // z>=0 after relu
    }
    tile[lane][co] = outv;
  }
  __syncthreads();
  for (int chunk = t; chunk < 64 * (COP / 16); chunk += 256) {
    int px = chunk / (COP / 16), c16 = chunk % (COP / 16);
    int p = p0 + px;
    int n = p >> 10, hw = p & 1023, h = hw >> 5, w = hw & 31;
    size_t dst = (((size_t)n * 34 + h + 1) * 34 + (w + 1)) * COP + c16 * 16;
    *(uint4*)&q[dst] = *(const uint4*)&tile[px][c16 * 16];
  }
}

extern "C" void kernel_launch(void* const* d_in, const int* in_sizes, int n_in,
                              void* d_out, int out_size, void* d_ws, size_t ws_size,
                              hipStream_t stream) {
  const float* x = (const float*)d_in[0];
  float* out = (float*)d_out;
  char* ws = (char*)d_ws;

  // ---- workspace layout (total 97,053,696 B) ----
  if (ws_size < 97053696ull) return;
  char* xq  = ws;                            // [PTOT][192] i8        = 25,165,824 B
  char* xpq = ws + 25165824ull;              // pooled [PTOT][192] i8 (dies after b4)
  char* q2a = xpq;                           // reuse: [128][34][34][128] = 18,939,904 B
  char* q3a = ws + 44105728ull;              // [128][34][34][64] =  9,469,952 B
  char* q3b = ws + 53575680ull;              // [128][34][34][64] =  9,469,952 B
  u16* yh   = (u16*)(ws + 63045632ull);      // [<=128][PTOT] bf16    = 33,554,432 B
  char* bpk = ws + 96600064ull;              // packed i8 weights        224,256 B
  double* st = (double*)(ws + 96824320ull);  // 7 x NREP x 256 doubles   229,376 B

  hipMemsetAsync(st, 0, 7 * NREP * 256 * 8, stream);

  WPtrs wp;
  const int widx[7] = {1, 5, 9, 13, 17, 21, 25};
  for (int i = 0; i < 7; ++i) wp.p[i] = (const float*)d_in[widx[i]];
  wpack_kernel<<<876, 256, 0, stream>>>(wp, bpk);

  quantx_kernel<<<dim3(16, 3, 128), 256, 0, stream>>>(x, xq);
  pool_kernel<<<6144, 256, 0, stream>>>(xq, xpq);

  dim3 grd(1024), blk(256);
  double* stB[7];
  for (int b = 0; b < 7; ++b) stB[b] = st + (size_t)b * NREP * 256;

  // ---- b4 (slot 6): pooled 1x1 192->32, out 224..255 (xpq dies after) ----
  cstat_kernel<192, 1, 32, 4><<<grd, blk, 0, stream>>>(xpq, bpk + 218112, 2, 0,
                                                       stB[6], 0, yh);
  bnout_kernel<<<dim3(32, 32), 256, 0, stream>>>(yh, stB[6], (const float*)d_in[27],
                                                 (const float*)d_in[28], out, 224);

  // zero borders of padded q buffers (q2a aliases dead xpq)
  border_kernel<<<dim3(128, 3), 256, 0, stream>>>(q2a, q3a, q3b);

  // ---- b1 (slot 0): 1x1 192->64, out 0..63 ----
  cstat_kernel<192, 1, 64, 4><<<grd, blk, 0, stream>>>(xq, bpk + 0, 4, 0, stB[0], 0, yh);
  bnout_kernel<<<dim3(32, 64), 256, 0, stream>>>(yh, stB[0], (const float*)d_in[3],
                                                 (const float*)d_in[4], out, 0);

  // ---- b2a (slot 1): 1x1 192->96 -> q2a (COP=128, ch 96..127 zeroed) ----
  cstat_kernel<192, 1, 96, 4><<<grd, blk, 0, stream>>>(xq, bpk + 12288, 6, 0,
                                                       stB[1], 0, yh);
  bnqpad_kernel<96, 128><<<2048, 256, 0, stream>>>(yh, stB[1], (const float*)d_in[7],
                                                   (const float*)d_in[8], q2a);

  // ---- b2b (slot 2): 3x3 96(pad128)->128, out 64..191 ----
  cstat_kernel<128, 9, 128, 3><<<grd, blk, 0, stream>>>(q2a, bpk + 30720, 8, 0,
                                                        stB[2], 0, yh);
  bnout_kernel<<<dim3(32, 128), 256, 0, stream>>>(yh, stB[2], (const float*)d_in[11],
                                                  (const float*)d_in[12], out, 64);

  // ---- b3a (slot 3): 1x1 192->16 -> q3a (COP=64, upper 48 zero) ----
  cstat_kernel<192, 1, 16, 4><<<grd, blk, 0, stream>>>(xq, bpk + 178176, 1, 0,
                                                       stB[3], 0, yh);
  bnqpad_kernel<16, 64><<<2048, 256, 0, stream>>>(yh, stB[3], (const float*)d_in[15],
                                                  (const float*)d_in[16], q3a);

  // ---- b3b (slot 4): 3x3 16(pad64)->32 -> q3b (COP=64) ----
  cstat_kernel<64, 9, 32, 4><<<grd, blk, 0, stream>>>(q3a, bpk + 181248, 2, 0,
                                                      stB[4], 0, yh);
  bnqpad_kernel<32, 64><<<2048, 256, 0, stream>>>(yh, stB[4], (const float*)d_in[19],
                                                  (const float*)d_in[20], q3b);

  // ---- b3c (slot 5): 3x3 32(pad64)->32, out 192..223 ----
  cstat_kernel<64, 9, 32, 4><<<grd, blk, 0, stream>>>(q3b, bpk + 199680, 2, 0,
                                                      stB[5], 0, yh);
  bnout_kernel<<<dim3(32, 32), 256, 0, stream>>>(yh, stB[5], (const float*)d_in[23],
                                                 (const float*)d_in[24], out, 192);
}

// Round 10
// 241.174 us; speedup vs baseline: 1.9899x; 1.1253x over previous
//
#include <hip/hip_runtime.h>

typedef unsigned short u16;
typedef unsigned int u32;
typedef __attribute__((ext_vector_type(4))) int i32x4;
typedef __attribute__((ext_vector_type(4))) float f32x4;
typedef __attribute__((ext_vector_type(4))) u16 u16x4;
typedef __attribute__((ext_vector_type(8))) u16 u16x8;

#define PTOT 131072   // 128 images * 32*32 pixels
#define NREP 16       // stat accumulator replicas (atomic de-contention)

// ---------- helpers ----------
static __device__ __forceinline__ int qi8(float v) {  // round-half-even, clip +-127
  int q = (int)rintf(v * 128.f);
  return max(-127, min(127, q));
}
static __device__ __forceinline__ u16 bf_rne(float v) { // round-nearest-even bf16
  u32 u = __float_as_uint(v);
  u += 0x7fffu + ((u >> 16) & 1u);
  return (u16)(u >> 16);
}
static __device__ __forceinline__ float bf2f(u16 v) {
  return __uint_as_float((u32)v << 16);
}

// ---------- weight quantize + i8 MFMA fragment packing (row-linear K) ----------
// packed: [NCH][NF][64 lanes][16 B]; co = nf*16+(lane&15),
// k = c*64 + (lane>>4)*16 + j over row-linear K: r = k/KROWP, kk = k%KROWP;
// kk < 3*CIr -> (kh=r, kw=kk/CIr, ci=kk%CIr); else zero (row tail pad).
struct WPtrs { const float* p[7]; };

__global__ void wpack_kernel(WPtrs wp, char* __restrict__ o) {
  // {byte_off, CIr, KROWP, KH, Co}   (len = NCH*NF*1024)
  static const int S[7][5] = {
      {0,      192, 192, 1, 64},   // b1   NCH=3 NF=4  12288
      {12288,  192, 192, 1, 96},   // b2a  NCH=3 NF=6  18432
      {30720,  96,  320, 3, 128},  // b2b  NCH=15 NF=8 122880
      {153600, 192, 192, 1, 16},   // b3a  NCH=3 NF=1  3072
      {156672, 16,  64,  3, 32},   // b3b  NCH=3 NF=2  6144
      {162816, 32,  128, 3, 32},   // b3c  NCH=6 NF=2  12288
      {175104, 192, 192, 1, 32},   // b4   NCH=3 NF=2  6144
  };
  int idx = blockIdx.x * 256 + threadIdx.x;
  if (idx >= 181248) return;
  int s = 0;
#pragma unroll
  for (int i = 1; i < 7; ++i)
    if (idx >= S[i][0]) s = i;
  int local = idx - S[s][0];
  int CIr = S[s][1], KROWP = S[s][2], KH = S[s][3], Co = S[s][4];
  int j = local & 15, lane = (local >> 4) & 63, f = local >> 10;
  int NF = Co >> 4;
  int c = f / NF, nf = f - c * NF;
  int co = nf * 16 + (lane & 15);
  int k = c * 64 + ((lane >> 4) << 4) + j;
  int r = k / KROWP, kk = k - r * KROWP;
  char val = 0;
  if (kk < 3 * CIr || KH == 1) {
    int kw = (KH == 1) ? 0 : (kk / CIr);
    int ci = (KH == 1) ? kk : (kk - kw * CIr);
    val = (char)qi8(wp.p[s][(((size_t)co * CIr + ci) * KH + r) * KH + kw]);
  }
  o[idx] = val;
}

// ---------- quantize x: NCHW f32 -> NHWC int8 ----------
__global__ __launch_bounds__(256) void quantx_kernel(const float* __restrict__ x,
                                                     char* __restrict__ xq) {
  __shared__ __align__(16) char tile[64][80];
  int n = blockIdx.z, hwb = blockIdx.x * 64, cb = blockIdx.y * 64;
  int lane = threadIdx.x & 63, sub = threadIdx.x >> 6;
#pragma unroll
  for (int i = 0; i < 16; ++i) {
    int c = sub + i * 4;
    float v = x[(((size_t)n * 192 + cb + c) << 10) + hwb + lane];
    tile[lane][c] = (char)qi8(v);
  }
  __syncthreads();
  int t = threadIdx.x, px = t >> 2, c16 = t & 3;
  uint4 v = *(const uint4*)&tile[px][c16 * 16];
  *(uint4*)&xq[(((size_t)n << 10) + hwb + px) * 192 + cb + c16 * 16] = v;
}

// ---------- maxpool 3x3 s1 p1 on int8 NHWC ----------
__global__ __launch_bounds__(256) void pool_kernel(const char* __restrict__ xq,
                                                   char* __restrict__ xpq) {
  int idx = blockIdx.x * 256 + threadIdx.x;
  int c16 = idx % 12;
  int p = idx / 12;
  int n = p >> 10, hw = p & 1023, h = hw >> 5, w = hw & 31;
  int m[16];
#pragma unroll
  for (int j = 0; j < 16; ++j) m[j] = -127;
  for (int dh = -1; dh <= 1; ++dh) {
    int hh = h + dh; if (hh < 0 || hh > 31) continue;
    for (int dw = -1; dw <= 1; ++dw) {
      int ww = w + dw; if (ww < 0 || ww > 31) continue;
      uint4 v = *(const uint4*)&xq[((((size_t)n << 5) + hh) * 32 + ww) * 192 + c16 * 16];
      const char* bb = reinterpret_cast<const char*>(&v);
#pragma unroll
      for (int t = 0; t < 16; ++t) {
        int b = (int)bb[t];
        m[t] = b > m[t] ? b : m[t];
      }
    }
  }
  uint4 o;
  char* ob = reinterpret_cast<char*>(&o);
#pragma unroll
  for (int t = 0; t < 16; ++t) ob[t] = (char)m[t];
  *(uint4*)&xpq[(size_t)p * 192 + c16 * 16] = o;
}

// ---------- zero the 1-px borders of padded q buffers ----------
__global__ __launch_bounds__(256) void border_kernel(char* __restrict__ q2a,
                                                     char* __restrict__ q3a,
                                                     char* __restrict__ q3b) {
  int img = blockIdx.x, buf = blockIdx.y;
  char* base; int C;
  if (buf == 0) { base = q2a; C = 96; }
  else if (buf == 1) { base = q3a; C = 16; }
  else { base = q3b; C = 32; }
  char* ib = base + (size_t)img * 34 * 34 * C;
  int nch = C >> 4;
  uint4 z = {0, 0, 0, 0};
  for (int idx = threadIdx.x; idx < 132 * nch; idx += 256) {
    int b = idx / nch, cc = idx - b * nch;
    int h, w;
    if (b < 34) { h = 0; w = b; }
    else if (b < 68) { h = 33; w = b - 34; }
    else { int s = b - 68; h = 1 + (s >> 1); w = (s & 1) ? 33 : 0; }
    *(uint4*)(ib + ((h * 34 + w) * C + cc * 16)) = z;
  }
}

// ---------- i8 MFMA conv (row-linear K) + bf16 y-hat + fused stats ----------
// KK==1: xin [PTOT][CI]; KK==9: [128][34][34][CI] zero-padded, K-chunks walk
// each kh-row linearly (3*CI real bytes + zero-weight tail to KROWP).
// Row-tail reads overrun into cols w+3.. : in-bounds garbage * 0-weight = 0.
template <int CI, int KK, int KROWP, int COB, int WPEU>
__global__ __launch_bounds__(256, WPEU) void cstat_kernel(
    const char* __restrict__ xin, const char* __restrict__ bp, int nft, int nf0,
    double* __restrict__ stb, int cof, u16* __restrict__ yh) {
  constexpr int NCH = (KK == 1) ? CI / 64 : 3 * (KROWP / 64);
  constexpr int CPR = KROWP / 64;
  constexpr int NFW = COB / 16;
  constexpr int MF = 2;

  const int lane = threadIdx.x & 63;
  const int wave = threadIdx.x >> 6;
  const int mbase = blockIdx.x * 128 + wave * 32;

  uint abase[MF];
#pragma unroll
  for (int mf = 0; mf < MF; ++mf) {
    int p = mbase + mf * 16 + (lane & 15);
    if (KK == 1) {
      abase[mf] = (uint)p * CI;
    } else {
      int n = p >> 10, hw = p & 1023, h = hw >> 5, w = hw & 31;
      abase[mf] = (uint)((n * 34 + h) * 34 + w) * CI;
    }
  }
  const uint klane = (uint)(lane >> 4) * 16u;
  const uint blane = (uint)lane * 16u;

  i32x4 acc[MF][NFW];
#pragma unroll
  for (int i = 0; i < MF; ++i)
#pragma unroll
    for (int j = 0; j < NFW; ++j) acc[i][j] = {0, 0, 0, 0};

  auto chunk = [&](int c) {
    uint koff;
    if (KK == 1) {
      koff = (uint)c * 64u;
    } else {
      int r = c / CPR, o = (c - r * CPR) * 64;
      koff = (uint)(r * 34 * CI + o);
    }
    i32x4 af[MF];
#pragma unroll
    for (int mf = 0; mf < MF; ++mf)
      af[mf] = *(const i32x4*)(xin + (abase[mf] + koff + klane));
    i32x4 bfr[NFW];
#pragma unroll
    for (int nf = 0; nf < NFW; ++nf)
      bfr[nf] = *(const i32x4*)(bp + ((uint)((c * nft + nf0 + nf) * 1024) + blane));
#pragma unroll
    for (int mf = 0; mf < MF; ++mf)
#pragma unroll
      for (int nf = 0; nf < NFW; ++nf)
        acc[mf][nf] = __builtin_amdgcn_mfma_i32_16x16x64_i8(af[mf], bfr[nf],
                                                            acc[mf][nf], 0, 0, 0);
  };

  if (KK == 1) {
#pragma unroll
    for (int c = 0; c < NCH; ++c) chunk(c);
  } else {
#pragma unroll 3
    for (int c = 0; c < NCH; ++c) chunk(c);
  }

  // ---- convert to float y (exact), write y-hat bf16 planar ----
  float yv[MF][NFW][4];
#pragma unroll
  for (int mf = 0; mf < MF; ++mf)
#pragma unroll
    for (int nf = 0; nf < NFW; ++nf) {
      int col = nf * 16 + (lane & 15);
      int pix = mbase + mf * 16 + ((lane >> 4) << 2);
      u16x4 o;
#pragma unroll
      for (int r = 0; r < 4; ++r) {
        float v = (float)acc[mf][nf][r] * 6.103515625e-05f;  // 2^-14
        yv[mf][nf][r] = v;
        o[r] = bf_rne(v);
      }
      *(u16x4*)&yh[(size_t)col * PTOT + pix] = o;
    }

  // ---- per-channel stats -> replicated f64 atomics ----
  float s1[NFW], s2[NFW];
#pragma unroll
  for (int nf = 0; nf < NFW; ++nf) { s1[nf] = 0.f; s2[nf] = 0.f; }
#pragma unroll
  for (int mf = 0; mf < MF; ++mf)
#pragma unroll
    for (int nf = 0; nf < NFW; ++nf)
#pragma unroll
      for (int r = 0; r < 4; ++r) {
        float v = yv[mf][nf][r];
        s1[nf] += v;
        s2[nf] += v * v;
      }
#pragma unroll
  for (int m = 16; m <= 32; m <<= 1)
#pragma unroll
    for (int nf = 0; nf < NFW; ++nf) {
      s1[nf] += __shfl_xor(s1[nf], m);
      s2[nf] += __shfl_xor(s2[nf], m);
    }
  __shared__ float red[4][NFW][16][2];
  if (lane < 16)
#pragma unroll
    for (int nf = 0; nf < NFW; ++nf) {
      red[wave][nf][lane][0] = s1[nf];
      red[wave][nf][lane][1] = s2[nf];
    }
  __syncthreads();
  const int t = threadIdx.x;
  if (t < COB) {
    int nf = t >> 4, l = t & 15;
    float a = red[0][nf][l][0] + red[1][nf][l][0] + red[2][nf][l][0] + red[3][nf][l][0];
    float b = red[0][nf][l][1] + red[1][nf][l][1] + red[2][nf][l][1] + red[3][nf][l][1];
    int rep = blockIdx.x & (NREP - 1);
    atomicAdd(&stb[rep * 256 + 2 * (cof + t)], (double)a);
    atomicAdd(&stb[rep * 256 + 2 * (cof + t) + 1], (double)b);
  }
}

// ---------- BN+ReLU -> final f32 NCHW out ----------
__global__ __launch_bounds__(256) void bnout_kernel(const u16* __restrict__ yh,
                                                    const double* __restrict__ stb,
                                                    const float* __restrict__ g,
                                                    const float* __restrict__ be,
                                                    float* __restrict__ out, int cog) {
  int co = blockIdx.y, chunk = blockIdx.x, tid = threadIdx.x;
  double s1d = 0., s2d = 0.;
#pragma unroll
  for (int r = 0; r < NREP; ++r) {
    s1d += stb[r * 256 + 2 * co];
    s2d += stb[r * 256 + 2 * co + 1];
  }
  double m = s1d * (1.0 / PTOT);
  double v = s2d * (1.0 / PTOT) - m * m;
  double inv = 1.0 / sqrt(v + 1e-5);
  double c0d = (double)g[co] * inv;
  float c0 = (float)c0d;
  float c1 = (float)((double)be[co] - m * c0d);

  int p0 = chunk * 4096 + tid * 16;
  int n = p0 >> 10, hw = p0 & 1023;
  const u16* yp = yh + (size_t)co * PTOT + p0;
  float* op = out + (((size_t)(n * 256 + cog + co)) << 10) + hw;
#pragma unroll
  for (int half = 0; half < 2; ++half) {
    u16x8 r = *(const u16x8*)(yp + half * 8);
    f32x4 a, b;
#pragma unroll
    for (int e = 0; e < 4; ++e) {
      a[e] = fmaxf(fmaf(bf2f(r[e]), c0, c1), 0.f);
      b[e] = fmaxf(fmaf(bf2f(r[e + 4]), c0, c1), 0.f);
    }
    *(f32x4*)(op + half * 8) = a;
    *(f32x4*)(op + half * 8 + 4) = b;
  }
}

// ---------- BN+ReLU+quantize -> padded NHWC int8 ----------
template <int CO, int COP>
__global__ __launch_bounds__(256) void bnqpad_kernel(const u16* __restrict__ yh,
                                                     const double* __restrict__ stb,
                                                     const float* __restrict__ g,
                                                     const float* __restrict__ be,
                                                     char* __restrict__ q) {
  __shared__ float2 cfl[CO];
  __shared__ __align__(16) char tile[64][COP + 16];
  const int t = threadIdx.x;
  if (t < CO) {
    double s1d = 0., s2d = 0.;
#pragma unroll
    for (int r = 0; r < NREP; ++r) {
      s1d += stb[r * 256 + 2 * t];
      s2d += stb[r * 256 + 2 * t + 1];
    }
    double m = s1d * (1.0 / PTOT);
    double v = s2d * (1.0 / PTOT) - m * m;
    double inv = 1.0 / sqrt(v + 1e-5);
    double c0 = (double)g[t] * inv;
    cfl[t] = make_float2((float)c0, (float)((double)be[t] - m * c0));
  }
  __syncthreads();
  int p0 = blockIdx.x * 64;
  int lane = t & 63, sub = t >> 6;
#pragma unroll
  for (int i = 0; i < COP / 4; ++i) {
    int co = sub + i * 4;
    float2 cc = cfl[co];
    float z = fmaxf(fmaf(bf2f(yh[(size_t)co * PTOT + p0 + lane]), cc.x, cc.y), 0.f);
    tile[lane][co] = (char)min((int)rintf(z * 128.f), 127);  // z>=0 after relu
  }
  __syncthreads();
  for (int chunk = t; chunk < 64 * (COP / 16); chunk += 256) {
    int px = chunk / (COP / 16), c16 = chunk % (COP / 16);
    int p = p0 + px;
    int n = p >> 10, hw = p & 1023, h = hw >> 5, w = hw & 31;
    size_t dst = (((size_t)n * 34 + h + 1) * 34 + (w + 1)) * COP + c16 * 16;
    *(uint4*)&q[dst] = *(const uint4*)&tile[px][c16 * 16];
  }
}

extern "C" void kernel_launch(void* const* d_in, const int* in_sizes, int n_in,
                              void* d_out, int out_size, void* d_ws, size_t ws_size,
                              hipStream_t stream) {
  const float* x = (const float*)d_in[0];
  float* out = (float*)d_out;
  char* ws = (char*)d_ws;

  // ---- workspace layout (total 84,296,704 B) ----
  if (ws_size < 84296704ull) return;
  char* xq  = ws;                            // [PTOT][192] i8        = 25,165,824 B
  char* xpq = ws + 25165824ull;              // pooled [PTOT][192] i8 (dies after b4)
  char* q2a = xpq;                           // reuse: [128][34][34][96] +256 slack
  char* q3a = ws + 39371008ull;              // [128][34][34][16] +256
  char* q3b = ws + 41738752ull;              // [128][34][34][32] +256 (end 46,473,984)
  u16* yh   = (u16*)(ws + 50331648ull);      // [<=128][PTOT] bf16    = 33,554,432 B
  char* bpk = ws + 83886080ull;              // packed i8 weights        181,248 B
  double* st = (double*)(ws + 84067328ull);  // 7 x NREP x 256 doubles   229,376 B

  hipMemsetAsync(st, 0, 7 * NREP * 256 * 8, stream);

  WPtrs wp;
  const int widx[7] = {1, 5, 9, 13, 17, 21, 25};
  for (int i = 0; i < 7; ++i) wp.p[i] = (const float*)d_in[widx[i]];
  wpack_kernel<<<708, 256, 0, stream>>>(wp, bpk);

  quantx_kernel<<<dim3(16, 3, 128), 256, 0, stream>>>(x, xq);
  pool_kernel<<<6144, 256, 0, stream>>>(xq, xpq);

  dim3 grd(1024), blk(256);
  double* stB[7];
  for (int b = 0; b < 7; ++b) stB[b] = st + (size_t)b * NREP * 256;

  // ---- b4 (slot 6): pooled 1x1 192->32, out 224..255 (xpq dies after) ----
  cstat_kernel<192, 1, 192, 32, 4><<<grd, blk, 0, stream>>>(xpq, bpk + 175104, 2, 0,
                                                            stB[6], 0, yh);
  bnout_kernel<<<dim3(32, 32), 256, 0, stream>>>(yh, stB[6], (const float*)d_in[27],
                                                 (const float*)d_in[28], out, 224);

  // zero borders of padded q buffers (q2a aliases dead xpq)
  border_kernel<<<dim3(128, 3), 256, 0, stream>>>(q2a, q3a, q3b);

  // ---- b1 (slot 0): 1x1 192->64, out 0..63 ----
  cstat_kernel<192, 1, 192, 64, 4><<<grd, blk, 0, stream>>>(xq, bpk + 0, 4, 0,
                                                            stB[0], 0, yh);
  bnout_kernel<<<dim3(32, 64), 256, 0, stream>>>(yh, stB[0], (const float*)d_in[3],
                                                 (const float*)d_in[4], out, 0);

  // ---- b2a (slot 1): 1x1 192->96 -> q2a (COP=96) ----
  cstat_kernel<192, 1, 192, 96, 4><<<grd, blk, 0, stream>>>(xq, bpk + 12288, 6, 0,
                                                            stB[1], 0, yh);
  bnqpad_kernel<96, 96><<<2048, 256, 0, stream>>>(yh, stB[1], (const float*)d_in[7],
                                                  (const float*)d_in[8], q2a);

  // ---- b2b (slot 2): 3x3 96->128 row-linear K (KROWP=320), out 64..191 ----
  cstat_kernel<96, 9, 320, 128, 3><<<grd, blk, 0, stream>>>(q2a, bpk + 30720, 8, 0,
                                                            stB[2], 0, yh);
  bnout_kernel<<<dim3(32, 128), 256, 0, stream>>>(yh, stB[2], (const float*)d_in[11],
                                                  (const float*)d_in[12], out, 64);

  // ---- b3a (slot 3): 1x1 192->16 -> q3a (COP=16) ----
  cstat_kernel<192, 1, 192, 16, 4><<<grd, blk, 0, stream>>>(xq, bpk + 153600, 1, 0,
                                                            stB[3], 0, yh);
  bnqpad_kernel<16, 16><<<2048, 256, 0, stream>>>(yh, stB[3], (const float*)d_in[15],
                                                  (const float*)d_in[16], q3a);

  // ---- b3b (slot 4): 3x3 16->32 row-linear K (KROWP=64) -> q3b ----
  cstat_kernel<16, 9, 64, 32, 4><<<grd, blk, 0, stream>>>(q3a, bpk + 156672, 2, 0,
                                                          stB[4], 0, yh);
  bnqpad_kernel<32, 32><<<2048, 256, 0, stream>>>(yh, stB[4], (const float*)d_in[19],
                                                  (const float*)d_in[20], q3b);

  // ---- b3c (slot 5): 3x3 32->32 row-linear K (KROWP=128), out 192..223 ----
  cstat_kernel<32, 9, 128, 32, 4><<<grd, blk, 0, stream>>>(q3b, bpk + 162816, 2, 0,
                                                           stB[5], 0, yh);
  bnout_kernel<<<dim3(32, 32), 256, 0, stream>>>(yh, stB[5], (const float*)d_in[23],
                                                 (const float*)d_in[24], out, 192);
}